// Round 1
// baseline (410.969 us; speedup 1.0000x reference)
//
#include <hip/hip_runtime.h>
#include <hip/hip_bf16.h>

typedef __attribute__((ext_vector_type(8))) unsigned short ushort8;
typedef __attribute__((ext_vector_type(8))) short short8;
typedef __attribute__((ext_vector_type(4))) float f32x4;

#define DEV __device__ __forceinline__

DEV unsigned short f2bf(float f) {
    unsigned u = __builtin_bit_cast(unsigned, f);
    return (unsigned short)((u + 0x7fffu + ((u >> 16) & 1u)) >> 16);
}
DEV float bf2f(unsigned short h) {
    unsigned u = ((unsigned)h) << 16;
    return __builtin_bit_cast(float, u);
}
DEV float wred(float v) {
#pragma unroll
    for (int m = 32; m > 0; m >>= 1) v += __shfl_xor(v, m, 64);
    return v;
}

constexpr int B_ = 128, N_ = 512, D_ = 128, R_ = 512;
constexpr long NN2 = (long)N_ * N_;          // 262144
constexpr long BNN = (long)B_ * NN2;         // 33,554,432
constexpr long BND = (long)B_ * N_ * D_;     // 8,388,608

// ---------------- gathers ----------------

// one wave per row: gather rec_embed row, write raw f32 to out cols 128..639,
// write L2-normalized bf16 to feat
__global__ __launch_bounds__(256) void k_gather_app(const int* __restrict__ recd,
                                                    const float* __restrict__ table,
                                                    float* __restrict__ out,
                                                    unsigned short* __restrict__ feat) {
    int tid = threadIdx.x, lane = tid & 63, w = tid >> 6;
    long r = (long)blockIdx.x * 4 + w;   // 0..65535
    int tok = recd[r];
    const float* src = table + (long)tok * R_;
    int j = lane * 8;
    float4 v0 = *(const float4*)(src + j);
    float4 v1 = *(const float4*)(src + j + 4);
    float ssq = v0.x*v0.x + v0.y*v0.y + v0.z*v0.z + v0.w*v0.w
              + v1.x*v1.x + v1.y*v1.y + v1.z*v1.z + v1.w*v1.w;
    ssq = wred(ssq);
    float sc = 1.0f / fmaxf(sqrtf(ssq), 1e-12f);
    float* o = out + r * 640 + 128 + j;
    *(float4*)o = v0;
    *(float4*)(o + 4) = v1;
    ushort8 u;
    u[0]=f2bf(v0.x*sc); u[1]=f2bf(v0.y*sc); u[2]=f2bf(v0.z*sc); u[3]=f2bf(v0.w*sc);
    u[4]=f2bf(v1.x*sc); u[5]=f2bf(v1.y*sc); u[6]=f2bf(v1.z*sc); u[7]=f2bf(v1.w*sc);
    *(ushort8*)(feat + r * R_ + j) = u;
}

__global__ __launch_bounds__(256) void k_gather_x(const int* __restrict__ seq,
                                                  const float* __restrict__ table,
                                                  unsigned short* __restrict__ x) {
    long e8 = ((long)blockIdx.x * 256 + threadIdx.x) * 8;   // < BND
    long r = e8 >> 7;
    int d0 = (int)(e8 & 127);
    int tok = seq[r];
    const float* src = table + (long)tok * D_ + d0;
    float4 v0 = *(const float4*)src, v1 = *(const float4*)(src + 4);
    ushort8 u;
    u[0]=f2bf(v0.x); u[1]=f2bf(v0.y); u[2]=f2bf(v0.z); u[3]=f2bf(v0.w);
    u[4]=f2bf(v1.x); u[5]=f2bf(v1.y); u[6]=f2bf(v1.z); u[7]=f2bf(v1.w);
    *(ushort8*)(x + e8) = u;
}

// transpose cheb weights: wT[layer][mat][e][d] = w_layer[mat][d][e], bf16
__global__ __launch_bounds__(256) void k_wT(const float* __restrict__ w1,
                                            const float* __restrict__ w2,
                                            unsigned short* __restrict__ wT) {
    int o = blockIdx.x * 256 + threadIdx.x;   // < 98304
    int l = o / 49152;
    int rr = o - l * 49152;
    int mat = rr >> 14;
    int e2 = rr & 16383;
    int e = e2 >> 7, d = e2 & 127;
    const float* w = l ? w2 : w1;
    wT[o] = f2bf(w[mat * 16384 + d * 128 + e]);
}

// ---------------- bt-GEMM core (128x128 tile, BK=64, 4 waves) ----------------

DEV void stage_rowmajor(const unsigned short* base, long ld, int k0,
                        unsigned short* dst, int tid) {
#pragma unroll
    for (int i = 0; i < 4; ++i) {
        int u = i * 256 + tid;        // 0..1023 16B units
        int r = u >> 3, c = (u & 7) * 8;
        *(ushort8*)(dst + r * 64 + c) =
            *(const ushort8*)(base + (long)r * ld + k0 + c);
    }
}

// B-operand is [Nrows][128] row-major; tile needed is Bt[d][j] = B[k0+j][d]
DEV void stage_transposed(const unsigned short* t0, int k0, long ld,
                          unsigned short* dst, int tid) {
#pragma unroll
    for (int i = 0; i < 4; ++i) {
        int u = i * 256 + tid;          // 0..1023
        int j = u >> 4, d8 = (u & 15) * 8;
        ushort8 v = *(const ushort8*)(t0 + (long)(k0 + j) * ld + d8);
#pragma unroll
        for (int t = 0; t < 8; ++t) dst[(d8 + t) * 64 + j] = v[t];
    }
}

DEV void gemm_bt_core(const unsigned short* Abase, long ldA,
                      const unsigned short* Bbase, long ldB, int K,
                      unsigned short* As, unsigned short* Bs,
                      f32x4 acc[4][4], bool transposeB) {
    int tid = threadIdx.x, lane = tid & 63, wave = tid >> 6;
    int wm = wave >> 1, wn = wave & 1;
    int fr = lane & 15, ko = (lane >> 4) * 8;
    for (int k0 = 0; k0 < K; k0 += 64) {
        __syncthreads();
        stage_rowmajor(Abase, ldA, k0, As, tid);
        if (!transposeB) stage_rowmajor(Bbase, ldB, k0, Bs, tid);
        else             stage_transposed(Bbase, k0, ldB, Bs, tid);
        __syncthreads();
#pragma unroll
        for (int ks = 0; ks < 2; ++ks) {
            short8 a[4], b[4];
#pragma unroll
            for (int m = 0; m < 4; ++m)
                a[m] = *(const short8*)(As + (wm * 64 + m * 16 + fr) * 64 + ks * 32 + ko);
#pragma unroll
            for (int n = 0; n < 4; ++n)
                b[n] = *(const short8*)(Bs + (wn * 64 + n * 16 + fr) * 64 + ks * 32 + ko);
#pragma unroll
            for (int m = 0; m < 4; ++m)
#pragma unroll
                for (int n = 0; n < 4; ++n)
                    acc[m][n] = __builtin_amdgcn_mfma_f32_16x16x32_bf16(
                        a[m], b[n], acc[m][n], 0, 0, 0);
        }
    }
}

// ---------------- phase 2: A = feat feat^T, bf16 store + tile partials ----------------

__global__ __launch_bounds__(256) void k_adj(const unsigned short* __restrict__ feat,
                                             unsigned short* __restrict__ Abf,
                                             float* __restrict__ psum,
                                             float* __restrict__ pcnt) {
    __shared__ unsigned short As[128 * 64], Bs[128 * 64];
    __shared__ float sred[4], cred[4];
    int b = blockIdx.y;
    int tm = blockIdx.x >> 2, tn = blockIdx.x & 3;
    const unsigned short* fb = feat + (long)b * NN2;
    f32x4 acc[4][4] = {};
    gemm_bt_core(fb + (long)tm * 128 * R_, R_, fb + (long)tn * 128 * R_, R_, R_,
                 As, Bs, acc, false);
    int tid = threadIdx.x, lane = tid & 63, wave = tid >> 6;
    int wm = wave >> 1, wn = wave & 1;
    float s = 0.f, c = 0.f;
    unsigned short* Ab = Abf + (long)b * NN2;
#pragma unroll
    for (int m = 0; m < 4; ++m)
#pragma unroll
        for (int n = 0; n < 4; ++n) {
            f32x4 v = acc[m][n];
            int gj = tn * 128 + wn * 64 + n * 16 + (lane & 15);
            int gi0 = tm * 128 + wm * 64 + m * 16 + (lane >> 4) * 4;
#pragma unroll
            for (int q = 0; q < 4; ++q) {
                int gi = gi0 + q;
                Ab[(long)gi * N_ + gj] = f2bf(v[q]);
                if (gj > gi) {
                    s += v[q];
                    c += (v[q] != 0.0f) ? 1.0f : 0.0f;
                }
            }
        }
    s = wred(s);
    c = wred(c);
    if (lane == 0) { sred[wave] = s; cred[wave] = c; }
    __syncthreads();
    if (tid == 0) {
        psum[b * 16 + blockIdx.x] = sred[0] + sred[1] + sred[2] + sred[3];
        pcnt[b * 16 + blockIdx.x] = cred[0] + cred[1] + cred[2] + cred[3];
    }
}

__global__ void k_mean(const float* __restrict__ psum, const float* __restrict__ pcnt,
                       float* __restrict__ mean) {
    int b = threadIdx.x;
    if (b >= 128) return;
    float s = 0.f, c = 0.f;
    for (int t = 0; t < 16; ++t) { s += psum[b * 16 + t]; c += pcnt[b * 16 + t]; }
    mean[b] = s / fmaxf(c, 1.0f);
}

// one wave per row: deg -> dinv
__global__ __launch_bounds__(256) void k_deg(const unsigned short* __restrict__ Abf,
                                             const float* __restrict__ mean,
                                             float* __restrict__ dinv) {
    int tid = threadIdx.x, lane = tid & 63, w = tid >> 6;
    long r = (long)blockIdx.x * 4 + w;
    int b = (int)(r >> 9), i = (int)(r & 511);
    const unsigned short* row = Abf + r * N_;
    float m = mean[b];
    ushort8 v = *(const ushort8*)(row + lane * 8);
    int cnt = 0;
#pragma unroll
    for (int t = 0; t < 8; ++t) {
        float f = bf2f(v[t]);
        int j = lane * 8 + t;
        cnt += (f >= m && f != 0.0f && j != i) ? 1 : 0;
    }
    float fc = wred((float)cnt);
    if (lane == 0) dinv[r] = (fc > 0.f) ? rsqrtf(fc) : 0.f;
}

// in-place: S_ij = keep ? -(dinv_i*dinv_j) : 0  (element 1:1, aliasing safe)
__global__ __launch_bounds__(256) void k_buildS(unsigned short* __restrict__ Abf,
                                                const float* __restrict__ mean,
                                                const float* __restrict__ dinv) {
    long u = (long)blockIdx.x * 256 + threadIdx.x;  // < BNN/8
    long e = u * 8;
    int b = (int)(e >> 18);
    long w = e & (NN2 - 1);
    int i = (int)(w >> 9), j0 = (int)(w & 511);
    float m = mean[b], di = dinv[(long)b * N_ + i];
    const float* dj = dinv + (long)b * N_ + j0;
    ushort8 a = *(const ushort8*)(Abf + e);
    ushort8 o;
#pragma unroll
    for (int t = 0; t < 8; ++t) {
        float f = bf2f(a[t]);
        bool keep = (f >= m) && (f != 0.0f) && (j0 + t != i);
        o[t] = keep ? f2bf(-(di * dj[t])) : (unsigned short)0;
    }
    *(ushort8*)(Abf + e) = o;
}

// ---------------- cheb GEMMs ----------------

// MODE 0: out = S @ tin ; MODE 1: out = 2*(S @ tin) - t0
template <int MODE>
__global__ __launch_bounds__(256) void k_sx(const unsigned short* __restrict__ S,
                                            const unsigned short* __restrict__ tin,
                                            const unsigned short* __restrict__ t0,
                                            unsigned short* __restrict__ outbf) {
    __shared__ unsigned short As[128 * 64], Bs[128 * 64];
    int b = blockIdx.y, tm = blockIdx.x;
    f32x4 acc[4][4] = {};
    gemm_bt_core(S + (long)b * NN2 + (long)tm * 128 * N_, N_,
                 tin + (long)b * N_ * D_, D_, N_, As, Bs, acc, true);
    int tid = threadIdx.x, lane = tid & 63, wave = tid >> 6;
    int wm = wave >> 1, wn = wave & 1;
    unsigned short* ob = outbf + (long)b * N_ * D_;
    const unsigned short* t0b = t0 + (long)b * N_ * D_;
#pragma unroll
    for (int m = 0; m < 4; ++m)
#pragma unroll
        for (int n = 0; n < 4; ++n) {
            int gj = wn * 64 + n * 16 + (lane & 15);
            int gi0 = tm * 128 + wm * 64 + m * 16 + (lane >> 4) * 4;
#pragma unroll
            for (int q = 0; q < 4; ++q) {
                int gi = gi0 + q;
                float v = acc[m][n][q];
                if (MODE == 1) v = 2.0f * v - bf2f(t0b[(long)gi * D_ + gj]);
                ob[(long)gi * D_ + gj] = f2bf(v);
            }
        }
}

// y = relu(t0 w0 + t1 w1 + t2 w2 + b); LAYER 1 -> bf16 y; LAYER 2 -> f32 out cols 0..127
template <int LAYER>
__global__ __launch_bounds__(256) void k_proj(const unsigned short* __restrict__ t0,
                                              const unsigned short* __restrict__ t1,
                                              const unsigned short* __restrict__ t2,
                                              const unsigned short* __restrict__ wT,
                                              const float* __restrict__ bias,
                                              unsigned short* __restrict__ ybf,
                                              float* __restrict__ out) {
    __shared__ unsigned short As[128 * 64], Bs[128 * 64];
    long row0 = (long)blockIdx.x * 128;
    f32x4 acc[4][4] = {};
    gemm_bt_core(t0 + row0 * D_, D_, wT,          D_, D_, As, Bs, acc, false);
    gemm_bt_core(t1 + row0 * D_, D_, wT + 16384,  D_, D_, As, Bs, acc, false);
    gemm_bt_core(t2 + row0 * D_, D_, wT + 32768,  D_, D_, As, Bs, acc, false);
    int tid = threadIdx.x, lane = tid & 63, wave = tid >> 6;
    int wm = wave >> 1, wn = wave & 1;
#pragma unroll
    for (int m = 0; m < 4; ++m)
#pragma unroll
        for (int n = 0; n < 4; ++n) {
            int gj = wn * 64 + n * 16 + (lane & 15);
            long gr0 = row0 + wm * 64 + m * 16 + (lane >> 4) * 4;
#pragma unroll
            for (int q = 0; q < 4; ++q) {
                long gr = gr0 + q;
                float v = fmaxf(acc[m][n][q] + bias[gj], 0.0f);
                if (LAYER == 1) ybf[gr * D_ + gj] = f2bf(v);
                else            out[gr * 640 + gj] = v;
            }
        }
}

// ---------------- host ----------------

extern "C" void kernel_launch(void* const* d_in, const int* in_sizes, int n_in,
                              void* d_out, int out_size, void* d_ws, size_t ws_size,
                              hipStream_t stream) {
    const int* seq    = (const int*)d_in[0];
    const int* recd   = (const int*)d_in[1];
    const float* etab = (const float*)d_in[2];
    const float* rtab = (const float*)d_in[3];
    const float* w1   = (const float*)d_in[4];
    const float* b1   = (const float*)d_in[5];
    const float* w2   = (const float*)d_in[6];
    const float* b2   = (const float*)d_in[7];
    float* out = (float*)d_out;
    char* ws = (char*)d_ws;

    // workspace layout (bytes):
    //   [0,64M)    A/S bf16 (BNN)
    //   [64M,128M) feat bf16 (BNN) during phases 1-2; reused: tx1 @64M, tx2 @80M, y @96M
    //   [128M,144M) x bf16 (BND)
    //   [144M, ..) wT + stats
    if (ws_size < 151470592u) return;   // need ~144.5 MiB

    unsigned short* Abf  = (unsigned short*)(ws);
    unsigned short* feat = (unsigned short*)(ws + 67108864);
    unsigned short* tx1  = (unsigned short*)(ws + 67108864);
    unsigned short* tx2  = (unsigned short*)(ws + 83886080);
    unsigned short* ybf  = (unsigned short*)(ws + 100663296);
    unsigned short* xbf  = (unsigned short*)(ws + 134217728);
    unsigned short* wT   = (unsigned short*)(ws + 150994944);  // 98304 elems
    float* psum = (float*)(ws + 151191552);
    float* pcnt = (float*)(ws + 151199744);
    float* mean = (float*)(ws + 151207936);
    float* dinv = (float*)(ws + 151208448);

    k_wT<<<384, 256, 0, stream>>>(w1, w2, wT);
    k_gather_app<<<16384, 256, 0, stream>>>(recd, rtab, out, feat);
    k_gather_x<<<4096, 256, 0, stream>>>(seq, etab, xbf);
    k_adj<<<dim3(16, 128), 256, 0, stream>>>(feat, Abf, psum, pcnt);
    k_mean<<<1, 128, 0, stream>>>(psum, pcnt, mean);
    k_deg<<<16384, 256, 0, stream>>>(Abf, mean, dinv);
    k_buildS<<<16384, 256, 0, stream>>>(Abf, mean, dinv);
    // layer 1 (t0 = x)
    k_sx<0><<<dim3(4, 128), 256, 0, stream>>>(Abf, xbf, xbf, tx1);
    k_sx<1><<<dim3(4, 128), 256, 0, stream>>>(Abf, tx1, xbf, tx2);
    k_proj<1><<<512, 256, 0, stream>>>(xbf, tx1, tx2, wT, b1, ybf, nullptr);
    // layer 2 (t0 = y)
    k_sx<0><<<dim3(4, 128), 256, 0, stream>>>(Abf, ybf, ybf, tx1);
    k_sx<1><<<dim3(4, 128), 256, 0, stream>>>(Abf, tx1, ybf, tx2);
    k_proj<2><<<512, 256, 0, stream>>>(ybf, tx1, tx2, wT + 49152, b2, nullptr, out);
}

// Round 2
// 353.783 us; speedup vs baseline: 1.1616x; 1.1616x over previous
//
#include <hip/hip_runtime.h>
#include <hip/hip_bf16.h>

typedef __attribute__((ext_vector_type(8))) unsigned short ushort8;
typedef __attribute__((ext_vector_type(8))) short short8;
typedef __attribute__((ext_vector_type(4))) float f32x4;

#define DEV __device__ __forceinline__

DEV unsigned short f2bf(float f) {
    unsigned u = __builtin_bit_cast(unsigned, f);
    return (unsigned short)((u + 0x7fffu + ((u >> 16) & 1u)) >> 16);
}
DEV float bf2f(unsigned short h) {
    unsigned u = ((unsigned)h) << 16;
    return __builtin_bit_cast(float, u);
}
DEV float wred(float v) {
#pragma unroll
    for (int m = 32; m > 0; m >>= 1) v += __shfl_xor(v, m, 64);
    return v;
}

constexpr int B_ = 128, N_ = 512, D_ = 128, R_ = 512;
constexpr long NN2 = (long)N_ * N_;          // 262144
constexpr long BND = (long)B_ * N_ * D_;     // 8,388,608

// async global->LDS, 16B per lane. LDS dest = wave-uniform base + lane*16.
DEV void gll16(const void* g, void* l) {
    __builtin_amdgcn_global_load_lds(
        (const __attribute__((address_space(1))) unsigned*)g,
        (__attribute__((address_space(3))) unsigned*)l, 16, 0, 0);
}

// ---------------- gathers ----------------

__global__ __launch_bounds__(256) void k_gather_app(const int* __restrict__ recd,
                                                    const float* __restrict__ table,
                                                    float* __restrict__ out,
                                                    unsigned short* __restrict__ feat) {
    int tid = threadIdx.x, lane = tid & 63, w = tid >> 6;
    long r = (long)blockIdx.x * 4 + w;   // 0..65535
    int tok = recd[r];
    const float* src = table + (long)tok * R_;
    int j = lane * 8;
    float4 v0 = *(const float4*)(src + j);
    float4 v1 = *(const float4*)(src + j + 4);
    float ssq = v0.x*v0.x + v0.y*v0.y + v0.z*v0.z + v0.w*v0.w
              + v1.x*v1.x + v1.y*v1.y + v1.z*v1.z + v1.w*v1.w;
    ssq = wred(ssq);
    float sc = 1.0f / fmaxf(sqrtf(ssq), 1e-12f);
    float* o = out + r * 640 + 128 + j;
    *(float4*)o = v0;
    *(float4*)(o + 4) = v1;
    ushort8 u;
    u[0]=f2bf(v0.x*sc); u[1]=f2bf(v0.y*sc); u[2]=f2bf(v0.z*sc); u[3]=f2bf(v0.w*sc);
    u[4]=f2bf(v1.x*sc); u[5]=f2bf(v1.y*sc); u[6]=f2bf(v1.z*sc); u[7]=f2bf(v1.w*sc);
    *(ushort8*)(feat + r * R_ + j) = u;
}

__global__ __launch_bounds__(256) void k_gather_x(const int* __restrict__ seq,
                                                  const float* __restrict__ table,
                                                  unsigned short* __restrict__ x) {
    long e8 = ((long)blockIdx.x * 256 + threadIdx.x) * 8;   // < BND
    long r = e8 >> 7;
    int d0 = (int)(e8 & 127);
    int tok = seq[r];
    const float* src = table + (long)tok * D_ + d0;
    float4 v0 = *(const float4*)src, v1 = *(const float4*)(src + 4);
    ushort8 u;
    u[0]=f2bf(v0.x); u[1]=f2bf(v0.y); u[2]=f2bf(v0.z); u[3]=f2bf(v0.w);
    u[4]=f2bf(v1.x); u[5]=f2bf(v1.y); u[6]=f2bf(v1.z); u[7]=f2bf(v1.w);
    *(ushort8*)(x + e8) = u;
}

// cheb weights -> bf16, transposed, algebraically folded:
//   m0 = (w[0]-w[2])^T, m1 = w[1]^T, m2 = (2*w[2])^T
// so y = relu(T0 m0 + T1 m1 + U m2 + b) with U = S@T1 (no T2 materialization).
__global__ __launch_bounds__(256) void k_wT(const float* __restrict__ w1,
                                            const float* __restrict__ w2,
                                            unsigned short* __restrict__ wT) {
    int o = blockIdx.x * 256 + threadIdx.x;   // < 98304
    int l = o / 49152;
    int rr = o - l * 49152;
    int mat = rr >> 14;
    int e2 = rr & 16383;
    int e = e2 >> 7, d = e2 & 127;
    const float* w = l ? w2 : w1;
    float v;
    if (mat == 0)      v = w[d * 128 + e] - w[32768 + d * 128 + e];
    else if (mat == 1) v = w[16384 + d * 128 + e];
    else               v = 2.0f * w[32768 + d * 128 + e];
    wT[o] = f2bf(v);
}

// ---------------- transpose [b][512][128] -> [b][128][512], bf16 ----------------
// 64(n) x 128(d) tiles, XOR-swizzled LDS (group g' = g ^ ((n>>3)&7)) so the
// column-wise read phase hits 8 distinct banks.
__global__ __launch_bounds__(256) void k_tr(const unsigned short* __restrict__ in,
                                            unsigned short* __restrict__ out) {
    __shared__ unsigned short t[64 * 128];
    int b = blockIdx.x >> 3, tn = blockIdx.x & 7;
    const unsigned short* ib = in + ((long)b * 512 + tn * 64) * 128;
    unsigned short* ob = out + (long)b * 128 * 512 + tn * 64;
    int tid = threadIdx.x;
#pragma unroll
    for (int i = 0; i < 4; ++i) {
        int u = i * 256 + tid;          // 1024 ushort8 units
        int n = u >> 4, g = u & 15;
        ushort8 v = *(const ushort8*)(ib + n * 128 + g * 8);
        int gs = g ^ ((n >> 3) & 7);
        *(ushort8*)(t + n * 128 + gs * 8) = v;
    }
    __syncthreads();
#pragma unroll
    for (int i = 0; i < 4; ++i) {
        int u = i * 256 + tid;          // d = u>>3 (128 rows), n8 = (u&7)*8
        int d = u >> 3, n8 = (u & 7) * 8;
        ushort8 v;
#pragma unroll
        for (int tt = 0; tt < 8; ++tt) {
            int n = n8 + tt;
            int g = (d >> 3) ^ ((n >> 3) & 7);
            v[tt] = t[n * 128 + g * 8 + (d & 7)];
        }
        *(ushort8*)(ob + (long)d * 512 + n8) = v;
    }
}

// ---------------- bt-GEMM core (128x128 tile, BK=64, 4 waves) ----------------
// both operands row-major, K-contiguous; staged via global_load_lds dwordx4

DEV void stage_rowmajor(const unsigned short* base, long ld, int k0,
                        unsigned short* dst, int tid) {
#pragma unroll
    for (int i = 0; i < 4; ++i) {
        int u = i * 256 + tid;        // 0..1023 16B units
        int r = u >> 3, c = (u & 7) * 8;
        gll16(base + (long)r * ld + k0 + c,
              dst + i * 2048 + (tid & 448) * 8);   // wave-uniform LDS base
    }
}

DEV void gemm_bt_core(const unsigned short* Abase, long ldA,
                      const unsigned short* Bbase, long ldB, int K,
                      unsigned short* As, unsigned short* Bs,
                      f32x4 acc[4][4]) {
    int tid = threadIdx.x, lane = tid & 63, wave = tid >> 6;
    int wm = wave >> 1, wn = wave & 1;
    int fr = lane & 15, ko = (lane >> 4) * 8;
    for (int k0 = 0; k0 < K; k0 += 64) {
        __syncthreads();
        stage_rowmajor(Abase, ldA, k0, As, tid);
        stage_rowmajor(Bbase, ldB, k0, Bs, tid);
        __syncthreads();
#pragma unroll
        for (int ks = 0; ks < 2; ++ks) {
            short8 a[4], b[4];
#pragma unroll
            for (int m = 0; m < 4; ++m)
                a[m] = *(const short8*)(As + (wm * 64 + m * 16 + fr) * 64 + ks * 32 + ko);
#pragma unroll
            for (int n = 0; n < 4; ++n)
                b[n] = *(const short8*)(Bs + (wn * 64 + n * 16 + fr) * 64 + ks * 32 + ko);
#pragma unroll
            for (int m = 0; m < 4; ++m)
#pragma unroll
                for (int n = 0; n < 4; ++n)
                    acc[m][n] = __builtin_amdgcn_mfma_f32_16x16x32_bf16(
                        a[m], b[n], acc[m][n], 0, 0, 0);
        }
    }
}

// ---------------- adjacency: A = feat feat^T + strict-upper partials ----------------

__global__ __launch_bounds__(256) void k_adj(const unsigned short* __restrict__ feat,
                                             unsigned short* __restrict__ Abf,
                                             float* __restrict__ psum,
                                             float* __restrict__ pcnt) {
    __shared__ unsigned short As[128 * 64], Bs[128 * 64];
    __shared__ float sred[4], cred[4];
    int b = blockIdx.y;
    int tm = blockIdx.x >> 2, tn = blockIdx.x & 3;
    const unsigned short* fb = feat + (long)b * NN2;
    f32x4 acc[4][4] = {};
    gemm_bt_core(fb + (long)tm * 128 * R_, R_, fb + (long)tn * 128 * R_, R_, R_,
                 As, Bs, acc);
    int tid = threadIdx.x, lane = tid & 63, wave = tid >> 6;
    int wm = wave >> 1, wn = wave & 1;
    float s = 0.f, c = 0.f;
    unsigned short* Ab = Abf + (long)b * NN2;
#pragma unroll
    for (int m = 0; m < 4; ++m)
#pragma unroll
        for (int n = 0; n < 4; ++n) {
            f32x4 v = acc[m][n];
            int gj = tn * 128 + wn * 64 + n * 16 + (lane & 15);
            int gi0 = tm * 128 + wm * 64 + m * 16 + (lane >> 4) * 4;
#pragma unroll
            for (int q = 0; q < 4; ++q) {
                int gi = gi0 + q;
                Ab[(long)gi * N_ + gj] = f2bf(v[q]);
                if (gj > gi) {
                    s += v[q];
                    c += (v[q] != 0.0f) ? 1.0f : 0.0f;
                }
            }
        }
    s = wred(s);
    c = wred(c);
    if (lane == 0) { sred[wave] = s; cred[wave] = c; }
    __syncthreads();
    if (tid == 0) {
        psum[b * 16 + blockIdx.x] = sred[0] + sred[1] + sred[2] + sred[3];
        pcnt[b * 16 + blockIdx.x] = cred[0] + cred[1] + cred[2] + cred[3];
    }
}

__global__ void k_mean(const float* __restrict__ psum, const float* __restrict__ pcnt,
                       float* __restrict__ mean) {
    int b = threadIdx.x;
    if (b >= 128) return;
    float s = 0.f, c = 0.f;
    for (int t = 0; t < 16; ++t) { s += psum[b * 16 + t]; c += pcnt[b * 16 + t]; }
    mean[b] = s / fmaxf(c, 1.0f);
}

__global__ __launch_bounds__(256) void k_deg(const unsigned short* __restrict__ Abf,
                                             const float* __restrict__ mean,
                                             float* __restrict__ dinv) {
    int tid = threadIdx.x, lane = tid & 63, w = tid >> 6;
    long r = (long)blockIdx.x * 4 + w;
    int b = (int)(r >> 9), i = (int)(r & 511);
    const unsigned short* row = Abf + r * N_;
    float m = mean[b];
    ushort8 v = *(const ushort8*)(row + lane * 8);
    int cnt = 0;
#pragma unroll
    for (int t = 0; t < 8; ++t) {
        float f = bf2f(v[t]);
        int j = lane * 8 + t;
        cnt += (f >= m && f != 0.0f && j != i) ? 1 : 0;
    }
    float fc = wred((float)cnt);
    if (lane == 0) dinv[r] = (fc > 0.f) ? rsqrtf(fc) : 0.f;
}

// in-place: S_ij = keep ? -(dinv_i*dinv_j) : 0  (S is symmetric)
__global__ __launch_bounds__(256) void k_buildS(unsigned short* __restrict__ Abf,
                                                const float* __restrict__ mean,
                                                const float* __restrict__ dinv) {
    long u = (long)blockIdx.x * 256 + threadIdx.x;  // < BNN/8
    long e = u * 8;
    int b = (int)(e >> 18);
    long w = e & (NN2 - 1);
    int i = (int)(w >> 9), j0 = (int)(w & 511);
    float m = mean[b], di = dinv[(long)b * N_ + i];
    const float* dj = dinv + (long)b * N_ + j0;
    ushort8 a = *(const ushort8*)(Abf + e);
    ushort8 o;
#pragma unroll
    for (int t = 0; t < 8; ++t) {
        float f = bf2f(a[t]);
        bool keep = (f >= m) && (f != 0.0f) && (j0 + t != i);
        o[t] = keep ? f2bf(-(di * dj[t])) : (unsigned short)0;
    }
    *(ushort8*)(Abf + e) = o;
}

// ---------------- cheb GEMMs ----------------

// out[b][n][d] = sum_m S[b][n][m] * BT[b][d][m]   (BT row-major, K-contig)
__global__ __launch_bounds__(256) void k_sx(const unsigned short* __restrict__ S,
                                            const unsigned short* __restrict__ BT,
                                            unsigned short* __restrict__ outbf) {
    __shared__ unsigned short As[128 * 64], Bs[128 * 64];
    int b = blockIdx.y, tm = blockIdx.x;
    f32x4 acc[4][4] = {};
    gemm_bt_core(S + (long)b * NN2 + (long)tm * 128 * N_, N_,
                 BT + (long)b * (long)D_ * N_, N_, N_, As, Bs, acc);
    int tid = threadIdx.x, lane = tid & 63, wave = tid >> 6;
    int wm = wave >> 1, wn = wave & 1;
    unsigned short* ob = outbf + (long)b * N_ * D_;
#pragma unroll
    for (int m = 0; m < 4; ++m)
#pragma unroll
        for (int n = 0; n < 4; ++n) {
            int gj = wn * 64 + n * 16 + (lane & 15);
            int gi0 = tm * 128 + wm * 64 + m * 16 + (lane >> 4) * 4;
#pragma unroll
            for (int q = 0; q < 4; ++q)
                ob[(long)(gi0 + q) * D_ + gj] = f2bf(acc[m][n][q]);
        }
}

// y = relu(t0 m0 + t1 m1 + u m2 + b); LAYER 1 -> bf16 y; LAYER 2 -> f32 out cols 0..127
template <int LAYER>
__global__ __launch_bounds__(256) void k_proj(const unsigned short* __restrict__ t0,
                                              const unsigned short* __restrict__ t1,
                                              const unsigned short* __restrict__ t2,
                                              const unsigned short* __restrict__ wT,
                                              const float* __restrict__ bias,
                                              unsigned short* __restrict__ ybf,
                                              float* __restrict__ out) {
    __shared__ unsigned short As[128 * 64], Bs[128 * 64];
    long row0 = (long)blockIdx.x * 128;
    f32x4 acc[4][4] = {};
    gemm_bt_core(t0 + row0 * D_, D_, wT,          D_, D_, As, Bs, acc);
    gemm_bt_core(t1 + row0 * D_, D_, wT + 16384,  D_, D_, As, Bs, acc);
    gemm_bt_core(t2 + row0 * D_, D_, wT + 32768,  D_, D_, As, Bs, acc);
    int tid = threadIdx.x, lane = tid & 63, wave = tid >> 6;
    int wm = wave >> 1, wn = wave & 1;
#pragma unroll
    for (int m = 0; m < 4; ++m)
#pragma unroll
        for (int n = 0; n < 4; ++n) {
            int gj = wn * 64 + n * 16 + (lane & 15);
            long gr0 = row0 + wm * 64 + m * 16 + (lane >> 4) * 4;
#pragma unroll
            for (int q = 0; q < 4; ++q) {
                long gr = gr0 + q;
                float v = fmaxf(acc[m][n][q] + bias[gj], 0.0f);
                if (LAYER == 1) ybf[gr * D_ + gj] = f2bf(v);
                else            out[gr * 640 + gj] = v;
            }
        }
}

// ---------------- host ----------------

extern "C" void kernel_launch(void* const* d_in, const int* in_sizes, int n_in,
                              void* d_out, int out_size, void* d_ws, size_t ws_size,
                              hipStream_t stream) {
    const int* seq    = (const int*)d_in[0];
    const int* recd   = (const int*)d_in[1];
    const float* etab = (const float*)d_in[2];
    const float* rtab = (const float*)d_in[3];
    const float* w1   = (const float*)d_in[4];
    const float* b1   = (const float*)d_in[5];
    const float* w2   = (const float*)d_in[6];
    const float* b2   = (const float*)d_in[7];
    float* out = (float*)d_out;
    char* ws = (char*)d_ws;

    // workspace layout (bytes):
    //   [0,64M)        A/S bf16
    //   [64M,128M)     feat bf16 (dead after k_adj); then 16MB slots:
    //                  slot0 @64M: xT / yT   slot1 @80M: t1
    //                  slot2 @96M: t1T       slot3 @112M: u
    //   [128M,144M)    x bf16; reused as y (proj1 reads x rows then writes same rows)
    //   [144M, ..)     wT + stats
    if (ws_size < 151470592u) return;

    unsigned short* Abf  = (unsigned short*)(ws);
    unsigned short* feat = (unsigned short*)(ws + 67108864);
    unsigned short* xT   = (unsigned short*)(ws + 67108864);   // also yT
    unsigned short* t1   = (unsigned short*)(ws + 83886080);
    unsigned short* t1T  = (unsigned short*)(ws + 100663296);
    unsigned short* ub   = (unsigned short*)(ws + 117440512);
    unsigned short* xbf  = (unsigned short*)(ws + 134217728);  // also y
    unsigned short* wT   = (unsigned short*)(ws + 150994944);  // 98304 elems
    float* psum = (float*)(ws + 151191552);
    float* pcnt = (float*)(ws + 151199744);
    float* mean = (float*)(ws + 151207936);
    float* dinv = (float*)(ws + 151208448);

    k_wT<<<384, 256, 0, stream>>>(w1, w2, wT);
    k_gather_app<<<16384, 256, 0, stream>>>(recd, rtab, out, feat);
    k_gather_x<<<4096, 256, 0, stream>>>(seq, etab, xbf);
    k_adj<<<dim3(16, 128), 256, 0, stream>>>(feat, Abf, psum, pcnt);
    k_mean<<<1, 128, 0, stream>>>(psum, pcnt, mean);
    k_deg<<<16384, 256, 0, stream>>>(Abf, mean, dinv);
    k_buildS<<<16384, 256, 0, stream>>>(Abf, mean, dinv);
    // layer 1: T0 = x
    k_tr<<<1024, 256, 0, stream>>>(xbf, xT);                    // x -> xT
    k_sx<<<dim3(4, 128), 256, 0, stream>>>(Abf, xT, t1);        // t1 = S x
    k_tr<<<1024, 256, 0, stream>>>(t1, t1T);
    k_sx<<<dim3(4, 128), 256, 0, stream>>>(Abf, t1T, ub);       // u = S t1
    k_proj<1><<<512, 256, 0, stream>>>(xbf, t1, ub, wT, b1, xbf, nullptr);   // y -> xbf
    // layer 2: T0 = y
    k_tr<<<1024, 256, 0, stream>>>(xbf, xT);                    // y -> yT
    k_sx<<<dim3(4, 128), 256, 0, stream>>>(Abf, xT, t1);        // t1 = S y
    k_tr<<<1024, 256, 0, stream>>>(t1, t1T);
    k_sx<<<dim3(4, 128), 256, 0, stream>>>(Abf, t1T, ub);       // u = S t1
    k_proj<2><<<512, 256, 0, stream>>>(xbf, t1, ub, wT + 49152, b2, nullptr, out);
}

// Round 4
// 299.083 us; speedup vs baseline: 1.3741x; 1.1829x over previous
//
#include <hip/hip_runtime.h>
#include <hip/hip_bf16.h>

typedef __attribute__((ext_vector_type(8))) unsigned short ushort8;
typedef __attribute__((ext_vector_type(4))) unsigned short bf16x4;
typedef __attribute__((ext_vector_type(8))) short short8;
typedef __attribute__((ext_vector_type(4))) float f32x4;

#define DEV __device__ __forceinline__

DEV unsigned short f2bf(float f) {
    unsigned u = __builtin_bit_cast(unsigned, f);
    return (unsigned short)((u + 0x7fffu + ((u >> 16) & 1u)) >> 16);
}
DEV float bf2f(unsigned short h) {
    unsigned u = ((unsigned)h) << 16;
    return __builtin_bit_cast(float, u);
}
DEV float wred(float v) {
#pragma unroll
    for (int m = 32; m > 0; m >>= 1) v += __shfl_xor(v, m, 64);
    return v;
}

constexpr int N_ = 512, D_ = 128, R_ = 512;
constexpr long NN2 = (long)N_ * N_;          // 262144

// async global->LDS, 16B per lane. LDS dest = wave-uniform base + lane*16.
DEV void gll16(const void* g, void* l) {
    __builtin_amdgcn_global_load_lds(
        (const __attribute__((address_space(1))) unsigned*)g,
        (__attribute__((address_space(3))) unsigned*)l, 16, 0, 0);
}

// ---------------- gathers ----------------

__global__ __launch_bounds__(256) void k_gather_app(const int* __restrict__ recd,
                                                    const float* __restrict__ table,
                                                    float* __restrict__ out,
                                                    unsigned short* __restrict__ feat) {
    int tid = threadIdx.x, lane = tid & 63, w = tid >> 6;
    long r = (long)blockIdx.x * 4 + w;   // 0..65535
    int tok = recd[r];
    const float* src = table + (long)tok * R_;
    int j = lane * 8;
    float4 v0 = *(const float4*)(src + j);
    float4 v1 = *(const float4*)(src + j + 4);
    float ssq = v0.x*v0.x + v0.y*v0.y + v0.z*v0.z + v0.w*v0.w
              + v1.x*v1.x + v1.y*v1.y + v1.z*v1.z + v1.w*v1.w;
    ssq = wred(ssq);
    float sc = 1.0f / fmaxf(sqrtf(ssq), 1e-12f);
    float* o = out + r * 640 + 128 + j;
    *(float4*)o = v0;
    *(float4*)(o + 4) = v1;
    ushort8 u;
    u[0]=f2bf(v0.x*sc); u[1]=f2bf(v0.y*sc); u[2]=f2bf(v0.z*sc); u[3]=f2bf(v0.w*sc);
    u[4]=f2bf(v1.x*sc); u[5]=f2bf(v1.y*sc); u[6]=f2bf(v1.z*sc); u[7]=f2bf(v1.w*sc);
    *(ushort8*)(feat + r * R_ + j) = u;
}

__global__ __launch_bounds__(256) void k_gather_x(const int* __restrict__ seq,
                                                  const float* __restrict__ table,
                                                  unsigned short* __restrict__ x) {
    long e8 = ((long)blockIdx.x * 256 + threadIdx.x) * 8;
    long r = e8 >> 7;
    int d0 = (int)(e8 & 127);
    int tok = seq[r];
    const float* src = table + (long)tok * D_ + d0;
    float4 v0 = *(const float4*)src, v1 = *(const float4*)(src + 4);
    ushort8 u;
    u[0]=f2bf(v0.x); u[1]=f2bf(v0.y); u[2]=f2bf(v0.z); u[3]=f2bf(v0.w);
    u[4]=f2bf(v1.x); u[5]=f2bf(v1.y); u[6]=f2bf(v1.z); u[7]=f2bf(v1.w);
    *(ushort8*)(x + e8) = u;
}

// cheb weights -> bf16, transposed, folded: m0=(w0-w2)^T, m1=w1^T, m2=(2w2)^T
__global__ __launch_bounds__(256) void k_wT(const float* __restrict__ w1,
                                            const float* __restrict__ w2,
                                            unsigned short* __restrict__ wT) {
    int o = blockIdx.x * 256 + threadIdx.x;   // < 98304
    int l = o / 49152;
    int rr = o - l * 49152;
    int mat = rr >> 14;
    int e2 = rr & 16383;
    int e = e2 >> 7, d = e2 & 127;
    const float* w = l ? w2 : w1;
    float v;
    if (mat == 0)      v = w[d * 128 + e] - w[32768 + d * 128 + e];
    else if (mat == 1) v = w[16384 + d * 128 + e];
    else               v = 2.0f * w[32768 + d * 128 + e];
    wT[o] = f2bf(v);
}

// ---------------- scale+transpose: p0T[b][d][n] = dinv[b,n]*x[b][n][d] ----------------
__global__ __launch_bounds__(256) void k_trs(const unsigned short* __restrict__ in,
                                             const float* __restrict__ dinv,
                                             unsigned short* __restrict__ out) {
    __shared__ unsigned short t[64 * 128];
    int b = blockIdx.x >> 3, tn = blockIdx.x & 7;
    const unsigned short* ib = in + ((long)b * 512 + tn * 64) * 128;
    unsigned short* ob = out + (long)b * 65536 + tn * 64;
    int tid = threadIdx.x;
#pragma unroll
    for (int i = 0; i < 4; ++i) {
        int u = i * 256 + tid;          // 1024 ushort8 units
        int n = u >> 4, g = u & 15;
        float s = dinv[(long)b * 512 + tn * 64 + n];
        ushort8 v = *(const ushort8*)(ib + n * 128 + g * 8);
        ushort8 sv;
#pragma unroll
        for (int tt = 0; tt < 8; ++tt) sv[tt] = f2bf(bf2f(v[tt]) * s);
        int gs = g ^ ((n >> 3) & 7);
        *(ushort8*)(t + n * 128 + gs * 8) = sv;
    }
    __syncthreads();
#pragma unroll
    for (int i = 0; i < 4; ++i) {
        int u = i * 256 + tid;
        int d = u >> 3, n8 = (u & 7) * 8;
        ushort8 v;
#pragma unroll
        for (int tt = 0; tt < 8; ++tt) {
            int n = n8 + tt;
            int g = (d >> 3) ^ ((n >> 3) & 7);
            v[tt] = t[n * 128 + g * 8 + (d & 7)];
        }
        *(ushort8*)(ob + (long)d * 512 + n8) = v;
    }
}

// ---------------- bt-GEMM core (dense, used by k_adj / k_proj) ----------------

DEV void stage_rowmajor(const unsigned short* base, long ld, int k0,
                        unsigned short* dst, int tid) {
#pragma unroll
    for (int i = 0; i < 4; ++i) {
        int u = i * 256 + tid;        // 0..1023 16B units
        int r = u >> 3, c = (u & 7) * 8;
        gll16(base + (long)r * ld + k0 + c,
              dst + i * 2048 + (tid & 448) * 8);
    }
}

DEV void gemm_bt_core(const unsigned short* Abase, long ldA,
                      const unsigned short* Bbase, long ldB, int K,
                      unsigned short* As, unsigned short* Bs,
                      f32x4 acc[4][4]) {
    int tid = threadIdx.x, lane = tid & 63, wave = tid >> 6;
    int wm = wave >> 1, wn = wave & 1;
    int fr = lane & 15, ko = (lane >> 4) * 8;
    for (int k0 = 0; k0 < K; k0 += 64) {
        __syncthreads();
        stage_rowmajor(Abase, ldA, k0, As, tid);
        stage_rowmajor(Bbase, ldB, k0, Bs, tid);
        __syncthreads();
#pragma unroll
        for (int ks = 0; ks < 2; ++ks) {
            short8 a[4], b[4];
#pragma unroll
            for (int m = 0; m < 4; ++m)
                a[m] = *(const short8*)(As + (wm * 64 + m * 16 + fr) * 64 + ks * 32 + ko);
#pragma unroll
            for (int n = 0; n < 4; ++n)
                b[n] = *(const short8*)(Bs + (wn * 64 + n * 16 + fr) * 64 + ks * 32 + ko);
#pragma unroll
            for (int m = 0; m < 4; ++m)
#pragma unroll
                for (int n = 0; n < 4; ++n)
                    acc[m][n] = __builtin_amdgcn_mfma_f32_16x16x32_bf16(
                        a[m], b[n], acc[m][n], 0, 0, 0);
        }
    }
}

// ---------------- adjacency: A = feat feat^T + strict-upper partials ----------------

__global__ __launch_bounds__(256) void k_adj(const unsigned short* __restrict__ feat,
                                             unsigned short* __restrict__ Abf,
                                             float* __restrict__ psum,
                                             float* __restrict__ pcnt) {
    __shared__ unsigned short As[128 * 64], Bs[128 * 64];
    __shared__ float sred[4], cred[4];
    int b = blockIdx.y;
    int tm = blockIdx.x >> 2, tn = blockIdx.x & 3;
    const unsigned short* fb = feat + (long)b * NN2;
    f32x4 acc[4][4] = {};
    gemm_bt_core(fb + (long)tm * 128 * R_, R_, fb + (long)tn * 128 * R_, R_, R_,
                 As, Bs, acc);
    int tid = threadIdx.x, lane = tid & 63, wave = tid >> 6;
    int wm = wave >> 1, wn = wave & 1;
    float s = 0.f, c = 0.f;
    unsigned short* Ab = Abf + (long)b * NN2;
#pragma unroll
    for (int m = 0; m < 4; ++m)
#pragma unroll
        for (int n = 0; n < 4; ++n) {
            f32x4 v = acc[m][n];
            int gj = tn * 128 + wn * 64 + n * 16 + (lane & 15);
            int gi0 = tm * 128 + wm * 64 + m * 16 + (lane >> 4) * 4;
#pragma unroll
            for (int q = 0; q < 4; ++q) {
                int gi = gi0 + q;
                Ab[(long)gi * N_ + gj] = f2bf(v[q]);
                if (gj > gi) {
                    s += v[q];
                    c += (v[q] != 0.0f) ? 1.0f : 0.0f;
                }
            }
        }
    s = wred(s);
    c = wred(c);
    if (lane == 0) { sred[wave] = s; cred[wave] = c; }
    __syncthreads();
    if (tid == 0) {
        psum[b * 16 + blockIdx.x] = sred[0] + sred[1] + sred[2] + sred[3];
        pcnt[b * 16 + blockIdx.x] = cred[0] + cred[1] + cred[2] + cred[3];
    }
}

__global__ void k_mean(const float* __restrict__ psum, const float* __restrict__ pcnt,
                       float* __restrict__ mean) {
    int b = threadIdx.x;
    if (b >= 128) return;
    float s = 0.f, c = 0.f;
    for (int t = 0; t < 16; ++t) { s += psum[b * 16 + t]; c += pcnt[b * 16 + t]; }
    mean[b] = s / fmaxf(c, 1.0f);
}

// ---------------- deg + bitmask (mask embedded at each A-row's first 64B) ----------------
// wave w handles row r: reads the full 1KB row, emits dinv[r] and the 64B bitmask
// (bit j of ulong word (j>>6) = keep). Row's mask overwrites A[r][0..31] -- safe,
// the only reader/writer of row r is this wave, loads complete before the store.
__global__ __launch_bounds__(256) void k_degmask(unsigned short* __restrict__ Abf,
                                                 const float* __restrict__ mean,
                                                 float* __restrict__ dinv) {
    __shared__ unsigned char mb[4][64];
    int tid = threadIdx.x, lane = tid & 63, w = tid >> 6;
    long r = (long)blockIdx.x * 4 + w;
    int b = (int)(r >> 9), i = (int)(r & 511);
    const unsigned short* row = Abf + r * 512;
    float m = mean[b];
    ushort8 v = *(const ushort8*)(row + lane * 8);
    unsigned byt = 0;
    int cnt = 0;
#pragma unroll
    for (int t = 0; t < 8; ++t) {
        float f = bf2f(v[t]);
        int j = lane * 8 + t;
        bool keep = (f >= m) && (f != 0.0f) && (j != i);
        byt |= (keep ? 1u : 0u) << t;
        cnt += keep ? 1 : 0;
    }
    mb[w][lane] = (unsigned char)byt;
    float fc = wred((float)cnt);
    __syncthreads();
    if (lane < 8) {
        unsigned long long mword = *(const unsigned long long*)&mb[w][lane * 8];
        *(unsigned long long*)((unsigned char*)Abf + r * 1024 + lane * 8) = mword;
    }
    if (lane == 8) dinv[r] = (fc > 0.f) ? rsqrtf(fc) : 0.f;
}

// ---------------- masked S-GEMM: q = A_bin @ p ; outN = -dinv*q ; outT = -dinv^2*q (transposed) ----
// A-fragments synthesized IN REGISTERS from the bitmask (no S reads, no A-side LDS).
template <int WT>
__global__ __launch_bounds__(256) void k_sxm(const unsigned short* __restrict__ Abf,
                                             const float* __restrict__ dinv,
                                             const unsigned short* __restrict__ pT,
                                             unsigned short* __restrict__ outN,
                                             unsigned short* __restrict__ outT) {
    __shared__ unsigned short Bs[128 * 64];
    int b = blockIdx.y, tm = blockIdx.x;
    int tid = threadIdx.x, lane = tid & 63, wave = tid >> 6;
    int wm = wave >> 1, wn = wave & 1;
    int fr = lane & 15, ko = (lane >> 4) * 8;
    const unsigned char* mbase = (const unsigned char*)Abf + (long)b * 524288;
    const unsigned short* pb = pT + (long)b * 65536;
    f32x4 acc[4][4] = {};
    for (int k0 = 0; k0 < 512; k0 += 64) {
        __syncthreads();
        stage_rowmajor(pb, 512, k0, Bs, tid);
        unsigned long long mw[4];
#pragma unroll
        for (int m = 0; m < 4; ++m) {
            int row = tm * 128 + wm * 64 + m * 16 + fr;
            mw[m] = *(const unsigned long long*)(mbase + (long)row * 1024 + (k0 >> 3));
        }
        __syncthreads();
#pragma unroll
        for (int ks = 0; ks < 2; ++ks) {
            short8 a4[4], b4[4];
#pragma unroll
            for (int m = 0; m < 4; ++m) {
                unsigned w32 = (unsigned)(mw[m] >> (ks * 32));
                short8 av;
#pragma unroll
                for (int t = 0; t < 8; ++t)
                    av[t] = (short)(((w32 >> (ko + t)) & 1u) ? 0x3F80 : 0);
                a4[m] = av;
            }
#pragma unroll
            for (int n = 0; n < 4; ++n)
                b4[n] = *(const short8*)(Bs + (wn * 64 + n * 16 + fr) * 64 + ks * 32 + ko);
#pragma unroll
            for (int m = 0; m < 4; ++m)
#pragma unroll
                for (int n = 0; n < 4; ++n)
                    acc[m][n] = __builtin_amdgcn_mfma_f32_16x16x32_bf16(
                        a4[m], b4[n], acc[m][n], 0, 0, 0);
        }
    }
    unsigned short* on = outN + (long)b * 65536;
#pragma unroll
    for (int m = 0; m < 4; ++m) {
        int gi0 = tm * 128 + wm * 64 + m * 16 + ((lane >> 4) << 2);
        float4 dv = *(const float4*)(dinv + (long)b * 512 + gi0);
#pragma unroll
        for (int n = 0; n < 4; ++n) {
            int gj = wn * 64 + n * 16 + fr;
            bf16x4 tw;
#pragma unroll
            for (int q = 0; q < 4; ++q) {
                float dq = (&dv.x)[q];
                float t1v = -dq * acc[m][n][q];
                on[(long)(gi0 + q) * 128 + gj] = f2bf(t1v);
                tw[q] = f2bf(dq * t1v);
            }
            if (WT)
                *(bf16x4*)(outT + (long)b * 65536 + (long)gj * 512 + gi0) = tw;
        }
    }
}

// ---------------- projection ----------------
// y = relu(t0 m0 + t1 m1 + u m2 + bias)
// LAYER 1: write y bf16 (aliases t0 rows -- each block reads only its own rows first)
//          + dual-write pT[e][n] = dinv[n]*y[n][e] for the next S-GEMM
// LAYER 2: write f32 out cols 0..127
template <int LAYER>
__global__ __launch_bounds__(256) void k_proj(const unsigned short* __restrict__ t0,
                                              const unsigned short* __restrict__ t1,
                                              const unsigned short* __restrict__ u,
                                              const unsigned short* __restrict__ wT,
                                              const float* __restrict__ bias,
                                              const float* __restrict__ dinv,
                                              unsigned short* __restrict__ ybf,
                                              unsigned short* __restrict__ pTout,
                                              float* __restrict__ out) {
    __shared__ unsigned short As[128 * 64], Bs[128 * 64];
    long row0 = (long)blockIdx.x * 128;
    f32x4 acc[4][4] = {};
    gemm_bt_core(t0 + row0 * D_, D_, wT,          D_, D_, As, Bs, acc);
    gemm_bt_core(t1 + row0 * D_, D_, wT + 16384,  D_, D_, As, Bs, acc);
    gemm_bt_core(u  + row0 * D_, D_, wT + 32768,  D_, D_, As, Bs, acc);
    int tid = threadIdx.x, lane = tid & 63, wave = tid >> 6;
    int wm = wave >> 1, wn = wave & 1;
#pragma unroll
    for (int m = 0; m < 4; ++m) {
        long gr0 = row0 + wm * 64 + m * 16 + ((lane >> 4) << 2);
        float4 dv;
        if (LAYER == 1) dv = *(const float4*)(dinv + gr0);
#pragma unroll
        for (int n = 0; n < 4; ++n) {
            int gj = wn * 64 + n * 16 + (lane & 15);
            bf16x4 tw;
#pragma unroll
            for (int q = 0; q < 4; ++q) {
                long gr = gr0 + q;
                float v = fmaxf(acc[m][n][q] + bias[gj], 0.0f);
                if (LAYER == 1) {
                    ybf[gr * D_ + gj] = f2bf(v);
                    tw[q] = f2bf((&dv.x)[q] * v);
                } else {
                    out[gr * 640 + gj] = v;
                }
            }
            if (LAYER == 1)
                *(bf16x4*)(pTout + (gr0 >> 9) * 65536 + (long)gj * 512 + (gr0 & 511)) = tw;
        }
    }
}

// ---------------- host ----------------

extern "C" void kernel_launch(void* const* d_in, const int* in_sizes, int n_in,
                              void* d_out, int out_size, void* d_ws, size_t ws_size,
                              hipStream_t stream) {
    const int* seq    = (const int*)d_in[0];
    const int* recd   = (const int*)d_in[1];
    const float* etab = (const float*)d_in[2];
    const float* rtab = (const float*)d_in[3];
    const float* w1   = (const float*)d_in[4];
    const float* b1   = (const float*)d_in[5];
    const float* w2   = (const float*)d_in[6];
    const float* b2   = (const float*)d_in[7];
    float* out = (float*)d_out;
    char* ws = (char*)d_ws;

    // workspace layout (bytes):
    //   [0,64M)        A bf16 (+ per-row 64B bitmask embedded at row starts after degmask)
    //   [64M,128M)     feat bf16 (dead after k_adj); reused as 4x16MiB slots:
    //                    pTa @64M, pTb @80M, t1 @96M, u @112M
    //   [128M,144M)    x bf16 (becomes y after proj1)
    //   [144M,144.45M) wT + psum + pcnt + mean + dinv
    if (ws_size < 151470592u) return;

    unsigned short* Abf  = (unsigned short*)(ws);
    unsigned short* feat = (unsigned short*)(ws + 67108864);
    unsigned short* pTa  = (unsigned short*)(ws + 67108864);
    unsigned short* pTb  = (unsigned short*)(ws + 83886080);
    unsigned short* t1   = (unsigned short*)(ws + 100663296);
    unsigned short* ub   = (unsigned short*)(ws + 117440512);
    unsigned short* xbf  = (unsigned short*)(ws + 134217728);
    unsigned short* wT   = (unsigned short*)(ws + 150994944);
    float* psum = (float*)(ws + 151191552);
    float* pcnt = (float*)(ws + 151199744);
    float* mean = (float*)(ws + 151207936);
    float* dinv = (float*)(ws + 151208448);

    k_wT<<<384, 256, 0, stream>>>(w1, w2, wT);
    k_gather_app<<<16384, 256, 0, stream>>>(recd, rtab, out, feat);
    k_gather_x<<<4096, 256, 0, stream>>>(seq, etab, xbf);
    k_adj<<<dim3(16, 128), 256, 0, stream>>>(feat, Abf, psum, pcnt);
    k_mean<<<1, 128, 0, stream>>>(psum, pcnt, mean);
    k_degmask<<<16384, 256, 0, stream>>>(Abf, mean, dinv);
    // layer 1: t0 = x
    k_trs<<<1024, 256, 0, stream>>>(xbf, dinv, pTa);                     // p0T = (Dinv x)^T
    k_sxm<1><<<dim3(4, 128), 256, 0, stream>>>(Abf, dinv, pTa, t1, pTb); // t1 = S x, pTb = Dinv t1
    k_sxm<0><<<dim3(4, 128), 256, 0, stream>>>(Abf, dinv, pTb, ub, nullptr); // u = S t1
    k_proj<1><<<512, 256, 0, stream>>>(xbf, t1, ub, wT, b1, dinv, xbf, pTa, nullptr);
    // layer 2: t0 = y (= xbf), pTa = (Dinv y)^T
    k_sxm<1><<<dim3(4, 128), 256, 0, stream>>>(Abf, dinv, pTa, t1, pTb);
    k_sxm<0><<<dim3(4, 128), 256, 0, stream>>>(Abf, dinv, pTb, ub, nullptr);
    k_proj<2><<<512, 256, 0, stream>>>(xbf, t1, ub, wT + 49152, b2, dinv, nullptr, nullptr, out);
}

// Round 5
// 288.359 us; speedup vs baseline: 1.4252x; 1.0372x over previous
//
#include <hip/hip_runtime.h>
#include <hip/hip_bf16.h>

typedef __attribute__((ext_vector_type(8))) unsigned short ushort8;
typedef __attribute__((ext_vector_type(4))) unsigned short bf16x4;
typedef __attribute__((ext_vector_type(8))) short short8;
typedef __attribute__((ext_vector_type(4))) float f32x4;

#define DEV __device__ __forceinline__

DEV unsigned short f2bf(float f) {
    unsigned u = __builtin_bit_cast(unsigned, f);
    return (unsigned short)((u + 0x7fffu + ((u >> 16) & 1u)) >> 16);
}
DEV float bf2f(unsigned short h) {
    unsigned u = ((unsigned)h) << 16;
    return __builtin_bit_cast(float, u);
}
DEV float wred(float v) {
#pragma unroll
    for (int m = 32; m > 0; m >>= 1) v += __shfl_xor(v, m, 64);
    return v;
}

constexpr int N_ = 512, D_ = 128, R_ = 512;
constexpr long NN2 = (long)N_ * N_;          // 262144

// async global->LDS, 16B per lane. LDS dest = wave-uniform base + lane*16.
DEV void gll16(const void* g, void* l) {
    __builtin_amdgcn_global_load_lds(
        (const __attribute__((address_space(1))) unsigned*)g,
        (__attribute__((address_space(3))) unsigned*)l, 16, 0, 0);
}

// ---------------- gathers ----------------

__global__ __launch_bounds__(256) void k_gather_app(const int* __restrict__ recd,
                                                    const float* __restrict__ table,
                                                    float* __restrict__ out,
                                                    unsigned short* __restrict__ feat) {
    int tid = threadIdx.x, lane = tid & 63, w = tid >> 6;
    long r = (long)blockIdx.x * 4 + w;   // 0..65535
    int tok = recd[r];
    const float* src = table + (long)tok * R_;
    int j = lane * 8;
    float4 v0 = *(const float4*)(src + j);
    float4 v1 = *(const float4*)(src + j + 4);
    float ssq = v0.x*v0.x + v0.y*v0.y + v0.z*v0.z + v0.w*v0.w
              + v1.x*v1.x + v1.y*v1.y + v1.z*v1.z + v1.w*v1.w;
    ssq = wred(ssq);
    float sc = 1.0f / fmaxf(sqrtf(ssq), 1e-12f);
    float* o = out + r * 640 + 128 + j;
    *(float4*)o = v0;
    *(float4*)(o + 4) = v1;
    ushort8 u;
    u[0]=f2bf(v0.x*sc); u[1]=f2bf(v0.y*sc); u[2]=f2bf(v0.z*sc); u[3]=f2bf(v0.w*sc);
    u[4]=f2bf(v1.x*sc); u[5]=f2bf(v1.y*sc); u[6]=f2bf(v1.z*sc); u[7]=f2bf(v1.w*sc);
    *(ushort8*)(feat + r * R_ + j) = u;
}

__global__ __launch_bounds__(256) void k_gather_x(const int* __restrict__ seq,
                                                  const float* __restrict__ table,
                                                  unsigned short* __restrict__ x) {
    long e8 = ((long)blockIdx.x * 256 + threadIdx.x) * 8;
    long r = e8 >> 7;
    int d0 = (int)(e8 & 127);
    int tok = seq[r];
    const float* src = table + (long)tok * D_ + d0;
    float4 v0 = *(const float4*)src, v1 = *(const float4*)(src + 4);
    ushort8 u;
    u[0]=f2bf(v0.x); u[1]=f2bf(v0.y); u[2]=f2bf(v0.z); u[3]=f2bf(v0.w);
    u[4]=f2bf(v1.x); u[5]=f2bf(v1.y); u[6]=f2bf(v1.z); u[7]=f2bf(v1.w);
    *(ushort8*)(x + e8) = u;
}

// cheb weights -> bf16, transposed, folded: m0=(w0-w2)^T, m1=w1^T, m2=(2w2)^T
__global__ __launch_bounds__(256) void k_wT(const float* __restrict__ w1,
                                            const float* __restrict__ w2,
                                            unsigned short* __restrict__ wT) {
    int o = blockIdx.x * 256 + threadIdx.x;   // < 98304
    int l = o / 49152;
    int rr = o - l * 49152;
    int mat = rr >> 14;
    int e2 = rr & 16383;
    int e = e2 >> 7, d = e2 & 127;
    const float* w = l ? w2 : w1;
    float v;
    if (mat == 0)      v = w[d * 128 + e] - w[32768 + d * 128 + e];
    else if (mat == 1) v = w[16384 + d * 128 + e];
    else               v = 2.0f * w[32768 + d * 128 + e];
    wT[o] = f2bf(v);
}

// ---------------- scale+transpose: p0T[b][d][n] = dinv[b,n]*x[b][n][d] ----------------
__global__ __launch_bounds__(256) void k_trs(const unsigned short* __restrict__ in,
                                             const float* __restrict__ dinv,
                                             unsigned short* __restrict__ out) {
    __shared__ unsigned short t[64 * 128];
    int b = blockIdx.x >> 3, tn = blockIdx.x & 7;
    const unsigned short* ib = in + ((long)b * 512 + tn * 64) * 128;
    unsigned short* ob = out + (long)b * 65536 + tn * 64;
    int tid = threadIdx.x;
#pragma unroll
    for (int i = 0; i < 4; ++i) {
        int u = i * 256 + tid;          // 1024 ushort8 units
        int n = u >> 4, g = u & 15;
        float s = dinv[(long)b * 512 + tn * 64 + n];
        ushort8 v = *(const ushort8*)(ib + n * 128 + g * 8);
        ushort8 sv;
#pragma unroll
        for (int tt = 0; tt < 8; ++tt) sv[tt] = f2bf(bf2f(v[tt]) * s);
        int gs = g ^ ((n >> 3) & 7);
        *(ushort8*)(t + n * 128 + gs * 8) = sv;
    }
    __syncthreads();
#pragma unroll
    for (int i = 0; i < 4; ++i) {
        int u = i * 256 + tid;
        int d = u >> 3, n8 = (u & 7) * 8;
        ushort8 v;
#pragma unroll
        for (int tt = 0; tt < 8; ++tt) {
            int n = n8 + tt;
            int g = (d >> 3) ^ ((n >> 3) & 7);
            v[tt] = t[n * 128 + g * 8 + (d & 7)];
        }
        *(ushort8*)(ob + (long)d * 512 + n8) = v;
    }
}

// ---------------- bt-GEMM core (dense, used by k_adj / k_proj) ----------------

DEV void stage_rowmajor(const unsigned short* base, long ld, int k0,
                        unsigned short* dst, int tid) {
#pragma unroll
    for (int i = 0; i < 4; ++i) {
        int u = i * 256 + tid;        // 0..1023 16B units
        int r = u >> 3, c = (u & 7) * 8;
        gll16(base + (long)r * ld + k0 + c,
              dst + i * 2048 + (tid & 448) * 8);
    }
}

DEV void gemm_bt_core(const unsigned short* Abase, long ldA,
                      const unsigned short* Bbase, long ldB, int K,
                      unsigned short* As, unsigned short* Bs,
                      f32x4 acc[4][4]) {
    int tid = threadIdx.x, lane = tid & 63, wave = tid >> 6;
    int wm = wave >> 1, wn = wave & 1;
    int fr = lane & 15, ko = (lane >> 4) * 8;
    for (int k0 = 0; k0 < K; k0 += 64) {
        __syncthreads();
        stage_rowmajor(Abase, ldA, k0, As, tid);
        stage_rowmajor(Bbase, ldB, k0, Bs, tid);
        __syncthreads();
#pragma unroll
        for (int ks = 0; ks < 2; ++ks) {
            short8 a[4], b[4];
#pragma unroll
            for (int m = 0; m < 4; ++m)
                a[m] = *(const short8*)(As + (wm * 64 + m * 16 + fr) * 64 + ks * 32 + ko);
#pragma unroll
            for (int n = 0; n < 4; ++n)
                b[n] = *(const short8*)(Bs + (wn * 64 + n * 16 + fr) * 64 + ks * 32 + ko);
#pragma unroll
            for (int m = 0; m < 4; ++m)
#pragma unroll
                for (int n = 0; n < 4; ++n)
                    acc[m][n] = __builtin_amdgcn_mfma_f32_16x16x32_bf16(
                        a[m], b[n], acc[m][n], 0, 0, 0);
        }
    }
}

// ---------------- adjacency (symmetric): only upper tiles, mirror off-diag ----------------

__global__ __launch_bounds__(256) void k_adj(const unsigned short* __restrict__ feat,
                                             unsigned short* __restrict__ Abf,
                                             float* __restrict__ psum,
                                             float* __restrict__ pcnt) {
    __shared__ unsigned short As[128 * 64], Bs[128 * 64];
    __shared__ float sred[4], cred[4];
    int b = blockIdx.y;
    int t = blockIdx.x;                 // 0..9 upper-triangle tile id
    int tm = (t < 4) ? 0 : (t < 7) ? 1 : (t < 9) ? 2 : 3;
    int tn = t - (tm * (9 - tm)) / 2 + tm;
    const unsigned short* fb = feat + (long)b * NN2;
    f32x4 acc[4][4] = {};
    gemm_bt_core(fb + (long)tm * 128 * R_, R_, fb + (long)tn * 128 * R_, R_, R_,
                 As, Bs, acc);
    int tid = threadIdx.x, lane = tid & 63, wave = tid >> 6;
    int wm = wave >> 1, wn = wave & 1;
    float s = 0.f, c = 0.f;
    unsigned short* Ab = Abf + (long)b * NN2;
    bool diag = (tm == tn);
#pragma unroll
    for (int m = 0; m < 4; ++m)
#pragma unroll
        for (int n = 0; n < 4; ++n) {
            f32x4 v = acc[m][n];
            int gj = tn * 128 + wn * 64 + n * 16 + (lane & 15);
            int gi0 = tm * 128 + wm * 64 + m * 16 + (lane >> 4) * 4;
            bf16x4 tw;
#pragma unroll
            for (int q = 0; q < 4; ++q) {
                int gi = gi0 + q;
                unsigned short bv = f2bf(v[q]);
                Ab[(long)gi * N_ + gj] = bv;
                tw[q] = bv;
                if (gj > gi) {
                    s += v[q];
                    c += (v[q] != 0.0f) ? 1.0f : 0.0f;
                }
            }
            if (!diag)   // mirror: A[gj][gi0..gi0+3] (contiguous along gi)
                *(bf16x4*)(Ab + (long)gj * N_ + gi0) = tw;
        }
    s = wred(s);
    c = wred(c);
    if (lane == 0) { sred[wave] = s; cred[wave] = c; }
    __syncthreads();
    if (tid == 0) {
        psum[b * 16 + t] = sred[0] + sred[1] + sred[2] + sred[3];
        pcnt[b * 16 + t] = cred[0] + cred[1] + cred[2] + cred[3];
    }
}

__global__ void k_mean(const float* __restrict__ psum, const float* __restrict__ pcnt,
                       float* __restrict__ mean) {
    int b = threadIdx.x;
    if (b >= 128) return;
    float s = 0.f, c = 0.f;
    for (int t = 0; t < 10; ++t) { s += psum[b * 16 + t]; c += pcnt[b * 16 + t]; }
    mean[b] = s / fmaxf(c, 1.0f);
}

// ---------------- deg + bitmask (mask embedded at each A-row's first 64B) ----------------
__global__ __launch_bounds__(256) void k_degmask(unsigned short* __restrict__ Abf,
                                                 const float* __restrict__ mean,
                                                 float* __restrict__ dinv) {
    __shared__ unsigned char mb[4][64];
    int tid = threadIdx.x, lane = tid & 63, w = tid >> 6;
    long r = (long)blockIdx.x * 4 + w;
    int b = (int)(r >> 9), i = (int)(r & 511);
    const unsigned short* row = Abf + r * 512;
    float m = mean[b];
    ushort8 v = *(const ushort8*)(row + lane * 8);
    unsigned byt = 0;
    int cnt = 0;
#pragma unroll
    for (int t = 0; t < 8; ++t) {
        float f = bf2f(v[t]);
        int j = lane * 8 + t;
        bool keep = (f >= m) && (f != 0.0f) && (j != i);
        byt |= (keep ? 1u : 0u) << t;
        cnt += keep ? 1 : 0;
    }
    mb[w][lane] = (unsigned char)byt;
    float fc = wred((float)cnt);
    __syncthreads();
    if (lane < 8) {
        unsigned long long mword = *(const unsigned long long*)&mb[w][lane * 8];
        *(unsigned long long*)((unsigned char*)Abf + r * 1024 + lane * 8) = mword;
    }
    if (lane == 8) dinv[r] = (fc > 0.f) ? rsqrtf(fc) : 0.f;
}

// ---------------- masked S-GEMM with LDS LUT expansion ----------------
// q = A_bin @ p ; outN = -dinv*q ; outT = -dinv^2*q (transposed).
// A-fragments come from a 256x8 bf16 LUT in LDS: byte of the row bitmask ->
// 8 bf16 {0,1} elements via one ds_read_b128 (replaces ~5 VALU ops/element).
template <int WT>
__global__ __launch_bounds__(256) void k_sxm(const unsigned short* __restrict__ Abf,
                                             const float* __restrict__ dinv,
                                             const unsigned short* __restrict__ pT,
                                             unsigned short* __restrict__ outN,
                                             unsigned short* __restrict__ outT) {
    __shared__ __align__(16) unsigned short Bs[128 * 64];
    __shared__ __align__(16) unsigned short lut[256 * 8];
    int tid = threadIdx.x, lane = tid & 63, wave = tid >> 6;
    {   // each thread fills one LUT entry (256 threads, 256 entries)
        ushort8 e;
#pragma unroll
        for (int j = 0; j < 8; ++j) e[j] = ((tid >> j) & 1) ? (unsigned short)0x3F80 : (unsigned short)0;
        *(ushort8*)(lut + tid * 8) = e;
    }
    int b = blockIdx.y, tm = blockIdx.x;
    int wm = wave >> 1, wn = wave & 1;
    int fr = lane & 15, ko = (lane >> 4) * 8;
    const unsigned char* mbase = (const unsigned char*)Abf + (long)b * 524288;
    const unsigned short* pb = pT + (long)b * 65536;
    f32x4 acc[4][4] = {};
    for (int k0 = 0; k0 < 512; k0 += 64) {
        __syncthreads();    // first iter: also publishes the LUT
        stage_rowmajor(pb, 512, k0, Bs, tid);
        unsigned long long mw[4];
#pragma unroll
        for (int m = 0; m < 4; ++m) {
            int row = tm * 128 + wm * 64 + m * 16 + fr;
            mw[m] = *(const unsigned long long*)(mbase + (long)row * 1024 + (k0 >> 3));
        }
        __syncthreads();
#pragma unroll
        for (int ks = 0; ks < 2; ++ks) {
            short8 a4[4], b4[4];
#pragma unroll
            for (int m = 0; m < 4; ++m) {
                unsigned w32 = (unsigned)(mw[m] >> (ks * 32));
                unsigned byt = (w32 >> ko) & 255u;
                a4[m] = *(const short8*)(lut + byt * 8);
            }
#pragma unroll
            for (int n = 0; n < 4; ++n)
                b4[n] = *(const short8*)(Bs + (wn * 64 + n * 16 + fr) * 64 + ks * 32 + ko);
#pragma unroll
            for (int m = 0; m < 4; ++m)
#pragma unroll
                for (int n = 0; n < 4; ++n)
                    acc[m][n] = __builtin_amdgcn_mfma_f32_16x16x32_bf16(
                        a4[m], b4[n], acc[m][n], 0, 0, 0);
        }
    }
    unsigned short* on = outN + (long)b * 65536;
#pragma unroll
    for (int m = 0; m < 4; ++m) {
        int gi0 = tm * 128 + wm * 64 + m * 16 + ((lane >> 4) << 2);
        float4 dv = *(const float4*)(dinv + (long)b * 512 + gi0);
#pragma unroll
        for (int n = 0; n < 4; ++n) {
            int gj = wn * 64 + n * 16 + fr;
            bf16x4 tw;
#pragma unroll
            for (int q = 0; q < 4; ++q) {
                float dq = (&dv.x)[q];
                float t1v = -dq * acc[m][n][q];
                on[(long)(gi0 + q) * 128 + gj] = f2bf(t1v);
                tw[q] = f2bf(dq * t1v);
            }
            if (WT)
                *(bf16x4*)(outT + (long)b * 65536 + (long)gj * 512 + gi0) = tw;
        }
    }
}

// ---------------- projection ----------------
template <int LAYER>
__global__ __launch_bounds__(256) void k_proj(const unsigned short* __restrict__ t0,
                                              const unsigned short* __restrict__ t1,
                                              const unsigned short* __restrict__ u,
                                              const unsigned short* __restrict__ wT,
                                              const float* __restrict__ bias,
                                              const float* __restrict__ dinv,
                                              unsigned short* __restrict__ ybf,
                                              unsigned short* __restrict__ pTout,
                                              float* __restrict__ out) {
    __shared__ unsigned short As[128 * 64], Bs[128 * 64];
    long row0 = (long)blockIdx.x * 128;
    f32x4 acc[4][4] = {};
    gemm_bt_core(t0 + row0 * D_, D_, wT,          D_, D_, As, Bs, acc);
    gemm_bt_core(t1 + row0 * D_, D_, wT + 16384,  D_, D_, As, Bs, acc);
    gemm_bt_core(u  + row0 * D_, D_, wT + 32768,  D_, D_, As, Bs, acc);
    int tid = threadIdx.x, lane = tid & 63, wave = tid >> 6;
    int wm = wave >> 1, wn = wave & 1;
#pragma unroll
    for (int m = 0; m < 4; ++m) {
        long gr0 = row0 + wm * 64 + m * 16 + ((lane >> 4) << 2);
        float4 dv;
        if (LAYER == 1) dv = *(const float4*)(dinv + gr0);
#pragma unroll
        for (int n = 0; n < 4; ++n) {
            int gj = wn * 64 + n * 16 + (lane & 15);
            bf16x4 tw;
#pragma unroll
            for (int q = 0; q < 4; ++q) {
                long gr = gr0 + q;
                float v = fmaxf(acc[m][n][q] + bias[gj], 0.0f);
                if (LAYER == 1) {
                    ybf[gr * D_ + gj] = f2bf(v);
                    tw[q] = f2bf((&dv.x)[q] * v);
                } else {
                    out[gr * 640 + gj] = v;
                }
            }
            if (LAYER == 1)
                *(bf16x4*)(pTout + (gr0 >> 9) * 65536 + (long)gj * 512 + (gr0 & 511)) = tw;
        }
    }
}

// ---------------- host ----------------

extern "C" void kernel_launch(void* const* d_in, const int* in_sizes, int n_in,
                              void* d_out, int out_size, void* d_ws, size_t ws_size,
                              hipStream_t stream) {
    const int* seq    = (const int*)d_in[0];
    const int* recd   = (const int*)d_in[1];
    const float* etab = (const float*)d_in[2];
    const float* rtab = (const float*)d_in[3];
    const float* w1   = (const float*)d_in[4];
    const float* b1   = (const float*)d_in[5];
    const float* w2   = (const float*)d_in[6];
    const float* b2   = (const float*)d_in[7];
    float* out = (float*)d_out;
    char* ws = (char*)d_ws;

    if (ws_size < 151470592u) return;

    unsigned short* Abf  = (unsigned short*)(ws);
    unsigned short* feat = (unsigned short*)(ws + 67108864);
    unsigned short* pTa  = (unsigned short*)(ws + 67108864);
    unsigned short* pTb  = (unsigned short*)(ws + 83886080);
    unsigned short* t1   = (unsigned short*)(ws + 100663296);
    unsigned short* ub   = (unsigned short*)(ws + 117440512);
    unsigned short* xbf  = (unsigned short*)(ws + 134217728);
    unsigned short* wT   = (unsigned short*)(ws + 150994944);
    float* psum = (float*)(ws + 151191552);
    float* pcnt = (float*)(ws + 151199744);
    float* mean = (float*)(ws + 151207936);
    float* dinv = (float*)(ws + 151208448);

    k_wT<<<384, 256, 0, stream>>>(w1, w2, wT);
    k_gather_app<<<16384, 256, 0, stream>>>(recd, rtab, out, feat);
    k_gather_x<<<4096, 256, 0, stream>>>(seq, etab, xbf);
    k_adj<<<dim3(10, 128), 256, 0, stream>>>(feat, Abf, psum, pcnt);
    k_mean<<<1, 128, 0, stream>>>(psum, pcnt, mean);
    k_degmask<<<16384, 256, 0, stream>>>(Abf, mean, dinv);
    // layer 1: t0 = x
    k_trs<<<1024, 256, 0, stream>>>(xbf, dinv, pTa);                     // p0T = (Dinv x)^T
    k_sxm<1><<<dim3(4, 128), 256, 0, stream>>>(Abf, dinv, pTa, t1, pTb); // t1 = S x, pTb = Dinv t1
    k_sxm<0><<<dim3(4, 128), 256, 0, stream>>>(Abf, dinv, pTb, ub, nullptr); // u = S t1
    k_proj<1><<<512, 256, 0, stream>>>(xbf, t1, ub, wT, b1, dinv, xbf, pTa, nullptr);
    // layer 2: t0 = y (= xbf), pTa = (Dinv y)^T
    k_sxm<1><<<dim3(4, 128), 256, 0, stream>>>(Abf, dinv, pTa, t1, pTb);
    k_sxm<0><<<dim3(4, 128), 256, 0, stream>>>(Abf, dinv, pTb, ub, nullptr);
    k_proj<2><<<512, 256, 0, stream>>>(xbf, t1, ub, wT + 49152, b2, dinv, nullptr, nullptr, out);
}

// Round 6
// 269.904 us; speedup vs baseline: 1.5226x; 1.0684x over previous
//
#include <hip/hip_runtime.h>
#include <hip/hip_bf16.h>

typedef __attribute__((ext_vector_type(8))) unsigned short ushort8;
typedef __attribute__((ext_vector_type(4))) unsigned short bf16x4;
typedef __attribute__((ext_vector_type(8))) short short8;
typedef __attribute__((ext_vector_type(4))) float f32x4;
typedef __attribute__((ext_vector_type(2))) unsigned long long u64x2;

#define DEV __device__ __forceinline__

DEV unsigned short f2bf(float f) {
    unsigned u = __builtin_bit_cast(unsigned, f);
    return (unsigned short)((u + 0x7fffu + ((u >> 16) & 1u)) >> 16);
}
DEV float bf2f(unsigned short h) {
    unsigned u = ((unsigned)h) << 16;
    return __builtin_bit_cast(float, u);
}
DEV float wred(float v) {
#pragma unroll
    for (int m = 32; m > 0; m >>= 1) v += __shfl_xor(v, m, 64);
    return v;
}

constexpr int N_ = 512, D_ = 128, R_ = 512;
constexpr long NN2 = (long)N_ * N_;          // 262144

// async global->LDS, 16B per lane. LDS dest = wave-uniform base + lane*16.
DEV void gll16(const void* g, void* l) {
    __builtin_amdgcn_global_load_lds(
        (const __attribute__((address_space(1))) unsigned*)g,
        (__attribute__((address_space(3))) unsigned*)l, 16, 0, 0);
}

// ---------------- gathers ----------------

__global__ __launch_bounds__(256) void k_gather_app(const int* __restrict__ recd,
                                                    const float* __restrict__ table,
                                                    float* __restrict__ out,
                                                    unsigned short* __restrict__ feat) {
    int tid = threadIdx.x, lane = tid & 63, w = tid >> 6;
    long r = (long)blockIdx.x * 4 + w;   // 0..65535
    int tok = recd[r];
    const float* src = table + (long)tok * R_;
    int j = lane * 8;
    float4 v0 = *(const float4*)(src + j);
    float4 v1 = *(const float4*)(src + j + 4);
    float ssq = v0.x*v0.x + v0.y*v0.y + v0.z*v0.z + v0.w*v0.w
              + v1.x*v1.x + v1.y*v1.y + v1.z*v1.z + v1.w*v1.w;
    ssq = wred(ssq);
    float sc = 1.0f / fmaxf(sqrtf(ssq), 1e-12f);
    float* o = out + r * 640 + 128 + j;
    *(float4*)o = v0;
    *(float4*)(o + 4) = v1;
    ushort8 u;
    u[0]=f2bf(v0.x*sc); u[1]=f2bf(v0.y*sc); u[2]=f2bf(v0.z*sc); u[3]=f2bf(v0.w*sc);
    u[4]=f2bf(v1.x*sc); u[5]=f2bf(v1.y*sc); u[6]=f2bf(v1.z*sc); u[7]=f2bf(v1.w*sc);
    *(ushort8*)(feat + r * R_ + j) = u;
}

__global__ __launch_bounds__(256) void k_gather_x(const int* __restrict__ seq,
                                                  const float* __restrict__ table,
                                                  unsigned short* __restrict__ x) {
    long e8 = ((long)blockIdx.x * 256 + threadIdx.x) * 8;
    long r = e8 >> 7;
    int d0 = (int)(e8 & 127);
    int tok = seq[r];
    const float* src = table + (long)tok * D_ + d0;
    float4 v0 = *(const float4*)src, v1 = *(const float4*)(src + 4);
    ushort8 u;
    u[0]=f2bf(v0.x); u[1]=f2bf(v0.y); u[2]=f2bf(v0.z); u[3]=f2bf(v0.w);
    u[4]=f2bf(v1.x); u[5]=f2bf(v1.y); u[6]=f2bf(v1.z); u[7]=f2bf(v1.w);
    *(ushort8*)(x + e8) = u;
}

// cheb weights -> bf16, transposed, folded: m0=(w0-w2)^T, m1=w1^T, m2=(2w2)^T
__global__ __launch_bounds__(256) void k_wT(const float* __restrict__ w1,
                                            const float* __restrict__ w2,
                                            unsigned short* __restrict__ wT) {
    int o = blockIdx.x * 256 + threadIdx.x;   // < 98304
    int l = o / 49152;
    int rr = o - l * 49152;
    int mat = rr >> 14;
    int e2 = rr & 16383;
    int e = e2 >> 7, d = e2 & 127;
    const float* w = l ? w2 : w1;
    float v;
    if (mat == 0)      v = w[d * 128 + e] - w[32768 + d * 128 + e];
    else if (mat == 1) v = w[16384 + d * 128 + e];
    else               v = 2.0f * w[32768 + d * 128 + e];
    wT[o] = f2bf(v);
}

// ---------------- scale+transpose: p0T[b][d][n] = dinv[b,n]*x[b][n][d] ----------------
__global__ __launch_bounds__(256) void k_trs(const unsigned short* __restrict__ in,
                                             const float* __restrict__ dinv,
                                             unsigned short* __restrict__ out) {
    __shared__ unsigned short t[64 * 128];
    int b = blockIdx.x >> 3, tn = blockIdx.x & 7;
    const unsigned short* ib = in + ((long)b * 512 + tn * 64) * 128;
    unsigned short* ob = out + (long)b * 65536 + tn * 64;
    int tid = threadIdx.x;
#pragma unroll
    for (int i = 0; i < 4; ++i) {
        int u = i * 256 + tid;          // 1024 ushort8 units
        int n = u >> 4, g = u & 15;
        float s = dinv[(long)b * 512 + tn * 64 + n];
        ushort8 v = *(const ushort8*)(ib + n * 128 + g * 8);
        ushort8 sv;
#pragma unroll
        for (int tt = 0; tt < 8; ++tt) sv[tt] = f2bf(bf2f(v[tt]) * s);
        int gs = g ^ ((n >> 3) & 7);
        *(ushort8*)(t + n * 128 + gs * 8) = sv;
    }
    __syncthreads();
#pragma unroll
    for (int i = 0; i < 4; ++i) {
        int u = i * 256 + tid;
        int d = u >> 3, n8 = (u & 7) * 8;
        ushort8 v;
#pragma unroll
        for (int tt = 0; tt < 8; ++tt) {
            int n = n8 + tt;
            int g = (d >> 3) ^ ((n >> 3) & 7);
            v[tt] = t[n * 128 + g * 8 + (d & 7)];
        }
        *(ushort8*)(ob + (long)d * 512 + n8) = v;
    }
}

// ---------------- bt-GEMM core (dense, used by k_adj / k_proj) ----------------

DEV void stage_rowmajor(const unsigned short* base, long ld, int k0,
                        unsigned short* dst, int tid) {
#pragma unroll
    for (int i = 0; i < 4; ++i) {
        int u = i * 256 + tid;        // 0..1023 16B units
        int r = u >> 3, c = (u & 7) * 8;
        gll16(base + (long)r * ld + k0 + c,
              dst + i * 2048 + (tid & 448) * 8);
    }
}

DEV void gemm_bt_core(const unsigned short* Abase, long ldA,
                      const unsigned short* Bbase, long ldB, int K,
                      unsigned short* As, unsigned short* Bs,
                      f32x4 acc[4][4]) {
    int tid = threadIdx.x, lane = tid & 63, wave = tid >> 6;
    int wm = wave >> 1, wn = wave & 1;
    int fr = lane & 15, ko = (lane >> 4) * 8;
    for (int k0 = 0; k0 < K; k0 += 64) {
        __syncthreads();
        stage_rowmajor(Abase, ldA, k0, As, tid);
        stage_rowmajor(Bbase, ldB, k0, Bs, tid);
        __syncthreads();
#pragma unroll
        for (int ks = 0; ks < 2; ++ks) {
            short8 a[4], b[4];
#pragma unroll
            for (int m = 0; m < 4; ++m)
                a[m] = *(const short8*)(As + (wm * 64 + m * 16 + fr) * 64 + ks * 32 + ko);
#pragma unroll
            for (int n = 0; n < 4; ++n)
                b[n] = *(const short8*)(Bs + (wn * 64 + n * 16 + fr) * 64 + ks * 32 + ko);
#pragma unroll
            for (int m = 0; m < 4; ++m)
#pragma unroll
                for (int n = 0; n < 4; ++n)
                    acc[m][n] = __builtin_amdgcn_mfma_f32_16x16x32_bf16(
                        a[m], b[n], acc[m][n], 0, 0, 0);
        }
    }
}

// ---------------- adjacency (symmetric, upper tiles, XCD batch-affine) ----------------
// grid 1280 flat: r=g&7, q=g>>3; batch = r + 8*(q/10) (-> XCD r), tile t = q%10

__global__ __launch_bounds__(256) void k_adj(const unsigned short* __restrict__ feat,
                                             unsigned short* __restrict__ Abf,
                                             float* __restrict__ psum,
                                             float* __restrict__ pcnt) {
    __shared__ unsigned short As[128 * 64], Bs[128 * 64];
    __shared__ float sred[4], cred[4];
    int g = blockIdx.x;
    int r = g & 7, q = g >> 3;
    int q10 = q / 10;
    int b = r + (q10 << 3);
    int t = q - q10 * 10;               // 0..9 upper-triangle tile id
    int tm = (t < 4) ? 0 : (t < 7) ? 1 : (t < 9) ? 2 : 3;
    int tn = t - (tm * (9 - tm)) / 2 + tm;
    const unsigned short* fb = feat + (long)b * NN2;
    f32x4 acc[4][4] = {};
    gemm_bt_core(fb + (long)tm * 128 * R_, R_, fb + (long)tn * 128 * R_, R_, R_,
                 As, Bs, acc);
    int tid = threadIdx.x, lane = tid & 63, wave = tid >> 6;
    int wm = wave >> 1, wn = wave & 1;
    float s = 0.f, c = 0.f;
    unsigned short* Ab = Abf + (long)b * NN2;
    bool diag = (tm == tn);
#pragma unroll
    for (int m = 0; m < 4; ++m)
#pragma unroll
        for (int n = 0; n < 4; ++n) {
            f32x4 v = acc[m][n];
            int gj = tn * 128 + wn * 64 + n * 16 + (lane & 15);
            int gi0 = tm * 128 + wm * 64 + m * 16 + (lane >> 4) * 4;
            bf16x4 tw;
#pragma unroll
            for (int qq = 0; qq < 4; ++qq) {
                int gi = gi0 + qq;
                unsigned short bv = f2bf(v[qq]);
                Ab[(long)gi * N_ + gj] = bv;
                tw[qq] = bv;
                if (gj > gi) {
                    s += v[qq];
                    c += (v[qq] != 0.0f) ? 1.0f : 0.0f;
                }
            }
            if (!diag)   // mirror: A[gj][gi0..gi0+3] (contiguous along gi)
                *(bf16x4*)(Ab + (long)gj * N_ + gi0) = tw;
        }
    s = wred(s);
    c = wred(c);
    if (lane == 0) { sred[wave] = s; cred[wave] = c; }
    __syncthreads();
    if (tid == 0) {
        psum[b * 16 + t] = sred[0] + sred[1] + sred[2] + sred[3];
        pcnt[b * 16 + t] = cred[0] + cred[1] + cred[2] + cred[3];
    }
}

// ---------------- deg + bitmask, mean folded in ----------------
__global__ __launch_bounds__(256) void k_degmask(unsigned short* __restrict__ Abf,
                                                 const float* __restrict__ psum,
                                                 const float* __restrict__ pcnt,
                                                 float* __restrict__ dinv) {
    __shared__ unsigned char mb[4][64];
    int tid = threadIdx.x, lane = tid & 63, w = tid >> 6;
    long r = (long)blockIdx.x * 4 + w;
    int b = (int)(r >> 9), i = (int)(r & 511);
    float s = 0.f, c = 0.f;
#pragma unroll
    for (int t = 0; t < 10; ++t) { s += psum[b * 16 + t]; c += pcnt[b * 16 + t]; }
    float m = s / fmaxf(c, 1.0f);
    const unsigned short* row = Abf + r * 512;
    ushort8 v = *(const ushort8*)(row + lane * 8);
    unsigned byt = 0;
    int cnt = 0;
#pragma unroll
    for (int t = 0; t < 8; ++t) {
        float f = bf2f(v[t]);
        int j = lane * 8 + t;
        bool keep = (f >= m) && (f != 0.0f) && (j != i);
        byt |= (keep ? 1u : 0u) << t;
        cnt += keep ? 1 : 0;
    }
    mb[w][lane] = (unsigned char)byt;
    float fc = wred((float)cnt);
    __syncthreads();
    if (lane < 8) {
        unsigned long long mword = *(const unsigned long long*)&mb[w][lane * 8];
        *(unsigned long long*)((unsigned char*)Abf + r * 1024 + lane * 8) = mword;
    }
    if (lane == 8) dinv[r] = (fc > 0.f) ? rsqrtf(fc) : 0.f;
}

// ---------------- masked S-GEMM, nibble LUT (conflict-free), XCD batch-affine ----------------
// grid 512 flat: r=g&7, q=g>>3; batch = r + 8*(q>>2) (-> XCD r), tm = q&3.
// q = A_bin @ p ; outN = -dinv*q ; outT = -dinv^2*q (transposed).
template <int WT>
__global__ __launch_bounds__(256) void k_sxm(const unsigned short* __restrict__ Abf,
                                             const float* __restrict__ dinv,
                                             const unsigned short* __restrict__ pT,
                                             unsigned short* __restrict__ outN,
                                             unsigned short* __restrict__ outT) {
    __shared__ __align__(16) unsigned short Bs[128 * 64];
    __shared__ __align__(8) unsigned short lut4[16 * 4];
    int tid = threadIdx.x, lane = tid & 63, wave = tid >> 6;
    if (tid < 16) {   // nibble -> 4 bf16 {0,1}; entry nib on banks {2nib,2nib+1}: conflict-free
        unsigned long long e = 0;
#pragma unroll
        for (int j = 0; j < 4; ++j)
            if ((tid >> j) & 1) e |= 0x3F80ull << (16 * j);
        *(unsigned long long*)(lut4 + tid * 4) = e;
    }
    int g = blockIdx.x;
    int r = g & 7, q = g >> 3;
    int b = r + ((q >> 2) << 3);
    int tm = q & 3;
    int wm = wave >> 1, wn = wave & 1;
    int fr = lane & 15, ko = (lane >> 4) * 8;
    const unsigned char* mbase = (const unsigned char*)Abf + (long)b * 524288;
    const unsigned short* pb = pT + (long)b * 65536;
    f32x4 acc[4][4] = {};
    for (int k0 = 0; k0 < 512; k0 += 64) {
        __syncthreads();    // first iter: also publishes the LUT
        stage_rowmajor(pb, 512, k0, Bs, tid);
        unsigned long long mw[4];
#pragma unroll
        for (int m = 0; m < 4; ++m) {
            int row = tm * 128 + wm * 64 + m * 16 + fr;
            mw[m] = *(const unsigned long long*)(mbase + (long)row * 1024 + (k0 >> 3));
        }
        __syncthreads();
#pragma unroll
        for (int ks = 0; ks < 2; ++ks) {
            short8 a4[4], b4[4];
#pragma unroll
            for (int m = 0; m < 4; ++m) {
                unsigned w32 = (unsigned)(mw[m] >> (ks * 32));
                unsigned byt = (w32 >> ko) & 255u;
                unsigned long long lo = *(const unsigned long long*)(lut4 + (byt & 15u) * 4);
                unsigned long long hi = *(const unsigned long long*)(lut4 + (byt >> 4) * 4);
                u64x2 tt; tt[0] = lo; tt[1] = hi;
                a4[m] = __builtin_bit_cast(short8, tt);
            }
#pragma unroll
            for (int n = 0; n < 4; ++n)
                b4[n] = *(const short8*)(Bs + (wn * 64 + n * 16 + fr) * 64 + ks * 32 + ko);
#pragma unroll
            for (int m = 0; m < 4; ++m)
#pragma unroll
                for (int n = 0; n < 4; ++n)
                    acc[m][n] = __builtin_amdgcn_mfma_f32_16x16x32_bf16(
                        a4[m], b4[n], acc[m][n], 0, 0, 0);
        }
    }
    unsigned short* on = outN + (long)b * 65536;
#pragma unroll
    for (int m = 0; m < 4; ++m) {
        int gi0 = tm * 128 + wm * 64 + m * 16 + ((lane >> 4) << 2);
        float4 dv = *(const float4*)(dinv + (long)b * 512 + gi0);
#pragma unroll
        for (int n = 0; n < 4; ++n) {
            int gj = wn * 64 + n * 16 + fr;
            bf16x4 tw;
#pragma unroll
            for (int qq = 0; qq < 4; ++qq) {
                float dq = (&dv.x)[qq];
                float t1v = -dq * acc[m][n][qq];
                on[(long)(gi0 + qq) * 128 + gj] = f2bf(t1v);
                tw[qq] = f2bf(dq * t1v);
            }
            if (WT)
                *(bf16x4*)(outT + (long)b * 65536 + (long)gj * 512 + gi0) = tw;
        }
    }
}

// ---------------- projection ----------------
template <int LAYER>
__global__ __launch_bounds__(256) void k_proj(const unsigned short* __restrict__ t0,
                                              const unsigned short* __restrict__ t1,
                                              const unsigned short* __restrict__ u,
                                              const unsigned short* __restrict__ wT,
                                              const float* __restrict__ bias,
                                              const float* __restrict__ dinv,
                                              unsigned short* __restrict__ ybf,
                                              unsigned short* __restrict__ pTout,
                                              float* __restrict__ out) {
    __shared__ unsigned short As[128 * 64], Bs[128 * 64];
    long row0 = (long)blockIdx.x * 128;
    f32x4 acc[4][4] = {};
    gemm_bt_core(t0 + row0 * D_, D_, wT,          D_, D_, As, Bs, acc);
    gemm_bt_core(t1 + row0 * D_, D_, wT + 16384,  D_, D_, As, Bs, acc);
    gemm_bt_core(u  + row0 * D_, D_, wT + 32768,  D_, D_, As, Bs, acc);
    int tid = threadIdx.x, lane = tid & 63, wave = tid >> 6;
    int wm = wave >> 1, wn = wave & 1;
#pragma unroll
    for (int m = 0; m < 4; ++m) {
        long gr0 = row0 + wm * 64 + m * 16 + ((lane >> 4) << 2);
        float4 dv;
        if (LAYER == 1) dv = *(const float4*)(dinv + gr0);
#pragma unroll
        for (int n = 0; n < 4; ++n) {
            int gj = wn * 64 + n * 16 + (lane & 15);
            bf16x4 tw;
#pragma unroll
            for (int q = 0; q < 4; ++q) {
                long gr = gr0 + q;
                float v = fmaxf(acc[m][n][q] + bias[gj], 0.0f);
                if (LAYER == 1) {
                    ybf[gr * D_ + gj] = f2bf(v);
                    tw[q] = f2bf((&dv.x)[q] * v);
                } else {
                    out[gr * 640 + gj] = v;
                }
            }
            if (LAYER == 1)
                *(bf16x4*)(pTout + (gr0 >> 9) * 65536 + (long)gj * 512 + (gr0 & 511)) = tw;
        }
    }
}

// ---------------- host ----------------

extern "C" void kernel_launch(void* const* d_in, const int* in_sizes, int n_in,
                              void* d_out, int out_size, void* d_ws, size_t ws_size,
                              hipStream_t stream) {
    const int* seq    = (const int*)d_in[0];
    const int* recd   = (const int*)d_in[1];
    const float* etab = (const float*)d_in[2];
    const float* rtab = (const float*)d_in[3];
    const float* w1   = (const float*)d_in[4];
    const float* b1   = (const float*)d_in[5];
    const float* w2   = (const float*)d_in[6];
    const float* b2   = (const float*)d_in[7];
    float* out = (float*)d_out;
    char* ws = (char*)d_ws;

    if (ws_size < 151470592u) return;

    unsigned short* Abf  = (unsigned short*)(ws);
    unsigned short* feat = (unsigned short*)(ws + 67108864);
    unsigned short* pTa  = (unsigned short*)(ws + 67108864);
    unsigned short* pTb  = (unsigned short*)(ws + 83886080);
    unsigned short* t1   = (unsigned short*)(ws + 100663296);
    unsigned short* ub   = (unsigned short*)(ws + 117440512);
    unsigned short* xbf  = (unsigned short*)(ws + 134217728);
    unsigned short* wT   = (unsigned short*)(ws + 150994944);
    float* psum = (float*)(ws + 151191552);
    float* pcnt = (float*)(ws + 151199744);
    float* dinv = (float*)(ws + 151208448);

    k_wT<<<384, 256, 0, stream>>>(w1, w2, wT);
    k_gather_app<<<16384, 256, 0, stream>>>(recd, rtab, out, feat);
    k_gather_x<<<4096, 256, 0, stream>>>(seq, etab, xbf);
    k_adj<<<1280, 256, 0, stream>>>(feat, Abf, psum, pcnt);
    k_degmask<<<16384, 256, 0, stream>>>(Abf, psum, pcnt, dinv);
    // layer 1: t0 = x
    k_trs<<<1024, 256, 0, stream>>>(xbf, dinv, pTa);                 // p0T = (Dinv x)^T
    k_sxm<1><<<512, 256, 0, stream>>>(Abf, dinv, pTa, t1, pTb);      // t1 = S x, pTb = (Dinv t1)^T
    k_sxm<0><<<512, 256, 0, stream>>>(Abf, dinv, pTb, ub, nullptr);  // u = S t1
    k_proj<1><<<512, 256, 0, stream>>>(xbf, t1, ub, wT, b1, dinv, xbf, pTa, nullptr);
    // layer 2: t0 = y (= xbf), pTa = (Dinv y)^T
    k_sxm<1><<<512, 256, 0, stream>>>(Abf, dinv, pTa, t1, pTb);
    k_sxm<0><<<512, 256, 0, stream>>>(Abf, dinv, pTb, ub, nullptr);
    k_proj<2><<<512, 256, 0, stream>>>(xbf, t1, ub, wT + 49152, b2, dinv, nullptr, nullptr, out);
}

// Round 7
// 233.180 us; speedup vs baseline: 1.7625x; 1.1575x over previous
//
#include <hip/hip_runtime.h>
#include <hip/hip_bf16.h>

typedef __attribute__((ext_vector_type(8))) unsigned short ushort8;
typedef __attribute__((ext_vector_type(4))) unsigned short bf16x4;
typedef __attribute__((ext_vector_type(8))) short short8;
typedef __attribute__((ext_vector_type(4))) float f32x4;
typedef __attribute__((ext_vector_type(2))) unsigned long long u64x2;

#define DEV __device__ __forceinline__

DEV unsigned short f2bf(float f) {
    unsigned u = __builtin_bit_cast(unsigned, f);
    return (unsigned short)((u + 0x7fffu + ((u >> 16) & 1u)) >> 16);
}
DEV float bf2f(unsigned short h) {
    unsigned u = ((unsigned)h) << 16;
    return __builtin_bit_cast(float, u);
}
DEV float wred(float v) {
#pragma unroll
    for (int m = 32; m > 0; m >>= 1) v += __shfl_xor(v, m, 64);
    return v;
}

constexpr int N_ = 512, D_ = 128, R_ = 512;
constexpr long NN2 = (long)N_ * N_;          // 262144

// async global->LDS, 16B per lane. LDS dest = wave-uniform base + lane*16.
DEV void gll16(const void* g, void* l) {
    __builtin_amdgcn_global_load_lds(
        (const __attribute__((address_space(1))) unsigned*)g,
        (__attribute__((address_space(3))) unsigned*)l, 16, 0, 0);
}

// ---------------- fused front: gather_app | gather_x | wT ----------------

__global__ __launch_bounds__(256) void k_front(const int* __restrict__ recd,
                                               const float* __restrict__ rtab,
                                               const int* __restrict__ seq,
                                               const float* __restrict__ etab,
                                               const float* __restrict__ w1,
                                               const float* __restrict__ w2,
                                               float* __restrict__ out,
                                               unsigned short* __restrict__ feat,
                                               unsigned short* __restrict__ x,
                                               unsigned short* __restrict__ wT) {
    int bid = blockIdx.x, tid = threadIdx.x;
    if (bid < 16384) {                       // ---- gather_app ----
        int lane = tid & 63, w = tid >> 6;
        long r = (long)bid * 4 + w;
        int tok = recd[r];
        const float* src = rtab + (long)tok * R_;
        int j = lane * 8;
        float4 v0 = *(const float4*)(src + j);
        float4 v1 = *(const float4*)(src + j + 4);
        float ssq = v0.x*v0.x + v0.y*v0.y + v0.z*v0.z + v0.w*v0.w
                  + v1.x*v1.x + v1.y*v1.y + v1.z*v1.z + v1.w*v1.w;
        ssq = wred(ssq);
        float sc = 1.0f / fmaxf(sqrtf(ssq), 1e-12f);
        float* o = out + r * 640 + 128 + j;
        *(float4*)o = v0;
        *(float4*)(o + 4) = v1;
        ushort8 u;
        u[0]=f2bf(v0.x*sc); u[1]=f2bf(v0.y*sc); u[2]=f2bf(v0.z*sc); u[3]=f2bf(v0.w*sc);
        u[4]=f2bf(v1.x*sc); u[5]=f2bf(v1.y*sc); u[6]=f2bf(v1.z*sc); u[7]=f2bf(v1.w*sc);
        *(ushort8*)(feat + r * R_ + j) = u;
    } else if (bid < 20480) {                // ---- gather_x ----
        long e8 = ((long)(bid - 16384) * 256 + tid) * 8;
        long r = e8 >> 7;
        int d0 = (int)(e8 & 127);
        int tok = seq[r];
        const float* src = etab + (long)tok * D_ + d0;
        float4 v0 = *(const float4*)src, v1 = *(const float4*)(src + 4);
        ushort8 u;
        u[0]=f2bf(v0.x); u[1]=f2bf(v0.y); u[2]=f2bf(v0.z); u[3]=f2bf(v0.w);
        u[4]=f2bf(v1.x); u[5]=f2bf(v1.y); u[6]=f2bf(v1.z); u[7]=f2bf(v1.w);
        *(ushort8*)(x + e8) = u;
    } else {                                 // ---- wT (folded weights) ----
        int o = (bid - 20480) * 256 + tid;   // < 98304
        int l = o / 49152;
        int rr = o - l * 49152;
        int mat = rr >> 14;
        int e2 = rr & 16383;
        int e = e2 >> 7, d = e2 & 127;
        const float* w = l ? w2 : w1;
        float v;
        if (mat == 0)      v = w[d * 128 + e] - w[32768 + d * 128 + e];
        else if (mat == 1) v = w[16384 + d * 128 + e];
        else               v = 2.0f * w[32768 + d * 128 + e];
        wT[o] = f2bf(v);
    }
}

// ---------------- bt-GEMM core ----------------

DEV void stage_rowmajor(const unsigned short* base, long ld, int k0,
                        unsigned short* dst, int tid) {
#pragma unroll
    for (int i = 0; i < 4; ++i) {
        int u = i * 256 + tid;        // 0..1023 16B units
        int r = u >> 3, c = (u & 7) * 8;
        gll16(base + (long)r * ld + k0 + c,
              dst + i * 2048 + (tid & 448) * 8);
    }
}

// dual=false: B panel identical to A panel; stage once, read b-frags from As.
DEV void gemm_bt_core(const unsigned short* Abase, long ldA,
                      const unsigned short* Bbase, long ldB, int K,
                      unsigned short* As, unsigned short* Bs,
                      f32x4 acc[4][4], bool dual) {
    int tid = threadIdx.x, lane = tid & 63, wave = tid >> 6;
    int wm = wave >> 1, wn = wave & 1;
    int fr = lane & 15, ko = (lane >> 4) * 8;
    const unsigned short* Bsrc = dual ? Bs : As;
    for (int k0 = 0; k0 < K; k0 += 64) {
        __syncthreads();
        stage_rowmajor(Abase, ldA, k0, As, tid);
        if (dual) stage_rowmajor(Bbase, ldB, k0, Bs, tid);
        __syncthreads();
#pragma unroll
        for (int ks = 0; ks < 2; ++ks) {
            short8 a[4], b[4];
#pragma unroll
            for (int m = 0; m < 4; ++m)
                a[m] = *(const short8*)(As + (wm * 64 + m * 16 + fr) * 64 + ks * 32 + ko);
#pragma unroll
            for (int n = 0; n < 4; ++n)
                b[n] = *(const short8*)(Bsrc + (wn * 64 + n * 16 + fr) * 64 + ks * 32 + ko);
#pragma unroll
            for (int m = 0; m < 4; ++m)
#pragma unroll
                for (int n = 0; n < 4; ++n)
                    acc[m][n] = __builtin_amdgcn_mfma_f32_16x16x32_bf16(
                        a[m], b[n], acc[m][n], 0, 0, 0);
        }
    }
}

// ---------------- adjacency (symmetric, upper tiles, XCD batch-affine) ----------------

__global__ __launch_bounds__(256) void k_adj(const unsigned short* __restrict__ feat,
                                             unsigned short* __restrict__ Abf,
                                             float* __restrict__ psum,
                                             float* __restrict__ pcnt) {
    __shared__ unsigned short As[128 * 64], Bs[128 * 64];
    __shared__ float sred[4], cred[4];
    int g = blockIdx.x;
    int r = g & 7, q = g >> 3;
    int q10 = q / 10;
    int b = r + (q10 << 3);
    int t = q - q10 * 10;               // 0..9 upper-triangle tile id
    int tm = (t < 4) ? 0 : (t < 7) ? 1 : (t < 9) ? 2 : 3;
    int tn = t - (tm * (9 - tm)) / 2 + tm;
    bool diag = (tm == tn);
    const unsigned short* fb = feat + (long)b * NN2;
    f32x4 acc[4][4] = {};
    gemm_bt_core(fb + (long)tm * 128 * R_, R_, fb + (long)tn * 128 * R_, R_, R_,
                 As, Bs, acc, !diag);
    int tid = threadIdx.x, lane = tid & 63, wave = tid >> 6;
    int wm = wave >> 1, wn = wave & 1;
    float s = 0.f, c = 0.f;
    unsigned short* Ab = Abf + (long)b * NN2;
#pragma unroll
    for (int m = 0; m < 4; ++m)
#pragma unroll
        for (int n = 0; n < 4; ++n) {
            f32x4 v = acc[m][n];
            int gj = tn * 128 + wn * 64 + n * 16 + (lane & 15);
            int gi0 = tm * 128 + wm * 64 + m * 16 + (lane >> 4) * 4;
            bf16x4 tw;
#pragma unroll
            for (int qq = 0; qq < 4; ++qq) {
                int gi = gi0 + qq;
                unsigned short bv = f2bf(v[qq]);
                Ab[(long)gi * N_ + gj] = bv;
                tw[qq] = bv;
                if (gj > gi) {
                    s += v[qq];
                    c += (v[qq] != 0.0f) ? 1.0f : 0.0f;
                }
            }
            if (!diag)   // mirror: A[gj][gi0..gi0+3]
                *(bf16x4*)(Ab + (long)gj * N_ + gi0) = tw;
        }
    s = wred(s);
    c = wred(c);
    if (lane == 0) { sred[wave] = s; cred[wave] = c; }
    __syncthreads();
    if (tid == 0) {
        psum[b * 16 + t] = sred[0] + sred[1] + sred[2] + sred[3];
        pcnt[b * 16 + t] = cred[0] + cred[1] + cred[2] + cred[3];
    }
}

// ---------------- fused: mean + mask + dinv + scale-transpose ----------------
// block = (batch b, 64-row tile tn). Phase A: mean. Phase B: per-wave, 16 rows
// each: mask bits + degree (mask overwrites A-row head; row-private, race-free);
// dinv -> LDS + global. Phase C: p0T[d][n] = dinv[n]*x[n][d] via swizzled LDS.
__global__ __launch_bounds__(256) void k_degtrs(unsigned short* __restrict__ Abf,
                                                const float* __restrict__ psum,
                                                const float* __restrict__ pcnt,
                                                const unsigned short* __restrict__ xin,
                                                float* __restrict__ dinv,
                                                unsigned short* __restrict__ pT) {
    __shared__ unsigned char mb[4][64];
    __shared__ float sdinv[64];
    __shared__ unsigned short t[64 * 128];
    int bid = blockIdx.x;
    int b = bid >> 3, tn = bid & 7;
    int tid = threadIdx.x, lane = tid & 63, w = tid >> 6;
    float s = 0.f, c = 0.f;
#pragma unroll
    for (int k = 0; k < 10; ++k) { s += psum[b * 16 + k]; c += pcnt[b * 16 + k]; }
    float m = s / fmaxf(c, 1.0f);
#pragma unroll 1
    for (int i = 0; i < 16; ++i) {
        int rl = w * 16 + i;
        long r = (long)b * 512 + tn * 64 + rl;
        int ig = tn * 64 + rl;               // diagonal column for this row
        ushort8 v = *(const ushort8*)(Abf + r * 512 + lane * 8);
        unsigned byt = 0;
        int cnt = 0;
#pragma unroll
        for (int k = 0; k < 8; ++k) {
            float f = bf2f(v[k]);
            int j = lane * 8 + k;
            bool keep = (f >= m) && (f != 0.0f) && (j != ig);
            byt |= (keep ? 1u : 0u) << k;
            cnt += keep ? 1 : 0;
        }
        mb[w][lane] = (unsigned char)byt;
        float fc = wred((float)cnt);
        if (lane < 8) {
            unsigned long long mword = *(const unsigned long long*)&mb[w][lane * 8];
            *(unsigned long long*)((unsigned char*)Abf + r * 1024 + lane * 8) = mword;
        }
        if (lane == 8) {
            float dv = (fc > 0.f) ? rsqrtf(fc) : 0.f;
            dinv[r] = dv;
            sdinv[rl] = dv;
        }
    }
    __syncthreads();
    // phase C: scale-transpose x tile [64n x 128d] -> pT[b][d][tn*64+n]
    const unsigned short* ib = xin + ((long)b * 512 + tn * 64) * 128;
    unsigned short* ob = pT + (long)b * 65536 + tn * 64;
#pragma unroll
    for (int i = 0; i < 4; ++i) {
        int u = i * 256 + tid;          // 1024 ushort8 units
        int n = u >> 4, g = u & 15;
        float sc = sdinv[n];
        ushort8 v = *(const ushort8*)(ib + n * 128 + g * 8);
        ushort8 sv;
#pragma unroll
        for (int tt = 0; tt < 8; ++tt) sv[tt] = f2bf(bf2f(v[tt]) * sc);
        int gs = g ^ ((n >> 3) & 7);
        *(ushort8*)(t + n * 128 + gs * 8) = sv;
    }
    __syncthreads();
#pragma unroll
    for (int i = 0; i < 4; ++i) {
        int u = i * 256 + tid;
        int d = u >> 3, n8 = (u & 7) * 8;
        ushort8 v;
#pragma unroll
        for (int tt = 0; tt < 8; ++tt) {
            int n = n8 + tt;
            int g = (d >> 3) ^ ((n >> 3) & 7);
            v[tt] = t[n * 128 + g * 8 + (d & 7)];
        }
        *(ushort8*)(ob + (long)d * 512 + n8) = v;
    }
}

// ---------------- masked S-GEMM (t1 pass): writes t1 + (Dinv t1)^T ----------------
__global__ __launch_bounds__(256) void k_sxm(const unsigned short* __restrict__ Abf,
                                             const float* __restrict__ dinv,
                                             const unsigned short* __restrict__ pT,
                                             unsigned short* __restrict__ outN,
                                             unsigned short* __restrict__ outT) {
    __shared__ __align__(16) unsigned short Bs[128 * 64];
    __shared__ __align__(8) unsigned short lut4[16 * 4];
    int tid = threadIdx.x, lane = tid & 63, wave = tid >> 6;
    if (tid < 16) {
        unsigned long long e = 0;
#pragma unroll
        for (int j = 0; j < 4; ++j)
            if ((tid >> j) & 1) e |= 0x3F80ull << (16 * j);
        *(unsigned long long*)(lut4 + tid * 4) = e;
    }
    int g = blockIdx.x;
    int r = g & 7, q = g >> 3;
    int b = r + ((q >> 2) << 3);
    int tm = q & 3;
    int wm = wave >> 1, wn = wave & 1;
    int fr = lane & 15, ko = (lane >> 4) * 8;
    const unsigned char* mbase = (const unsigned char*)Abf + (long)b * 524288;
    const unsigned short* pb = pT + (long)b * 65536;
    f32x4 acc[4][4] = {};
    for (int k0 = 0; k0 < 512; k0 += 64) {
        __syncthreads();
        stage_rowmajor(pb, 512, k0, Bs, tid);
        unsigned long long mw[4];
#pragma unroll
        for (int m = 0; m < 4; ++m) {
            int row = tm * 128 + wm * 64 + m * 16 + fr;
            mw[m] = *(const unsigned long long*)(mbase + (long)row * 1024 + (k0 >> 3));
        }
        __syncthreads();
#pragma unroll
        for (int ks = 0; ks < 2; ++ks) {
            short8 a4[4], b4[4];
#pragma unroll
            for (int m = 0; m < 4; ++m) {
                unsigned w32 = (unsigned)(mw[m] >> (ks * 32));
                unsigned byt = (w32 >> ko) & 255u;
                unsigned long long lo = *(const unsigned long long*)(lut4 + (byt & 15u) * 4);
                unsigned long long hi = *(const unsigned long long*)(lut4 + (byt >> 4) * 4);
                u64x2 tt; tt[0] = lo; tt[1] = hi;
                a4[m] = __builtin_bit_cast(short8, tt);
            }
#pragma unroll
            for (int n = 0; n < 4; ++n)
                b4[n] = *(const short8*)(Bs + (wn * 64 + n * 16 + fr) * 64 + ks * 32 + ko);
#pragma unroll
            for (int m = 0; m < 4; ++m)
#pragma unroll
                for (int n = 0; n < 4; ++n)
                    acc[m][n] = __builtin_amdgcn_mfma_f32_16x16x32_bf16(
                        a4[m], b4[n], acc[m][n], 0, 0, 0);
        }
    }
    unsigned short* on = outN + (long)b * 65536;
#pragma unroll
    for (int m = 0; m < 4; ++m) {
        int gi0 = tm * 128 + wm * 64 + m * 16 + ((lane >> 4) << 2);
        float4 dv = *(const float4*)(dinv + (long)b * 512 + gi0);
#pragma unroll
        for (int n = 0; n < 4; ++n) {
            int gj = wn * 64 + n * 16 + fr;
            bf16x4 tw;
#pragma unroll
            for (int qq = 0; qq < 4; ++qq) {
                float dq = (&dv.x)[qq];
                float t1v = -dq * acc[m][n][qq];
                on[(long)(gi0 + qq) * 128 + gj] = f2bf(t1v);
                tw[qq] = f2bf(dq * t1v);
            }
            *(bf16x4*)(outT + (long)b * 65536 + (long)gj * 512 + gi0) = tw;
        }
    }
}

// ---------------- fused: u = S t1 (masked, in-LDS) + 3-term projection ----------------
// block (b,tm): u rows [tm*128,+128) -> LDS [128][132] bf16; then
// y = relu(t0 m0 + t1 m1 + u m2 + bias). LAYER1: y->ybf + pT dual-write; LAYER2: out.
template <int LAYER>
__global__ __launch_bounds__(256) void k_sxp(const unsigned short* __restrict__ Abf,
                                             const float* __restrict__ dinv,
                                             const unsigned short* __restrict__ pTin,
                                             const unsigned short* __restrict__ t0,
                                             const unsigned short* __restrict__ t1,
                                             const unsigned short* __restrict__ wTl,
                                             const float* __restrict__ bias,
                                             unsigned short* __restrict__ ybf,
                                             unsigned short* __restrict__ pTout,
                                             float* __restrict__ out) {
    __shared__ __align__(16) unsigned short As[128 * 64], Bs[128 * 64];
    __shared__ __align__(16) unsigned short uLds[128 * 132];
    __shared__ __align__(8) unsigned short lut4[16 * 4];
    int tid = threadIdx.x, lane = tid & 63, wave = tid >> 6;
    if (tid < 16) {
        unsigned long long e = 0;
#pragma unroll
        for (int j = 0; j < 4; ++j)
            if ((tid >> j) & 1) e |= 0x3F80ull << (16 * j);
        *(unsigned long long*)(lut4 + tid * 4) = e;
    }
    int g = blockIdx.x;
    int r = g & 7, q = g >> 3;
    int b = r + ((q >> 2) << 3);
    int tm = q & 3;
    int wm = wave >> 1, wn = wave & 1;
    int fr = lane & 15, ko = (lane >> 4) * 8;
    // ---- phase 1: u-acc = A_bin @ pTin (rows tm*128..+128) ----
    {
        const unsigned char* mbase = (const unsigned char*)Abf + (long)b * 524288;
        const unsigned short* pb = pTin + (long)b * 65536;
        f32x4 acc[4][4] = {};
        for (int k0 = 0; k0 < 512; k0 += 64) {
            __syncthreads();
            stage_rowmajor(pb, 512, k0, Bs, tid);
            unsigned long long mw[4];
#pragma unroll
            for (int m = 0; m < 4; ++m) {
                int row = tm * 128 + wm * 64 + m * 16 + fr;
                mw[m] = *(const unsigned long long*)(mbase + (long)row * 1024 + (k0 >> 3));
            }
            __syncthreads();
#pragma unroll
            for (int ks = 0; ks < 2; ++ks) {
                short8 a4[4], b4[4];
#pragma unroll
                for (int m = 0; m < 4; ++m) {
                    unsigned w32 = (unsigned)(mw[m] >> (ks * 32));
                    unsigned byt = (w32 >> ko) & 255u;
                    unsigned long long lo = *(const unsigned long long*)(lut4 + (byt & 15u) * 4);
                    unsigned long long hi = *(const unsigned long long*)(lut4 + (byt >> 4) * 4);
                    u64x2 tt; tt[0] = lo; tt[1] = hi;
                    a4[m] = __builtin_bit_cast(short8, tt);
                }
#pragma unroll
                for (int n = 0; n < 4; ++n)
                    b4[n] = *(const short8*)(Bs + (wn * 64 + n * 16 + fr) * 64 + ks * 32 + ko);
#pragma unroll
                for (int m = 0; m < 4; ++m)
#pragma unroll
                    for (int n = 0; n < 4; ++n)
                        acc[m][n] = __builtin_amdgcn_mfma_f32_16x16x32_bf16(
                            a4[m], b4[n], acc[m][n], 0, 0, 0);
            }
        }
        // park u = bf16(-dinv * acc) in LDS [row][col], LD=132 (pad kills conflicts)
#pragma unroll
        for (int m = 0; m < 4; ++m) {
            int li0 = wm * 64 + m * 16 + ((lane >> 4) << 2);   // local row
            float4 dv = *(const float4*)(dinv + (long)b * 512 + tm * 128 + li0);
#pragma unroll
            for (int n = 0; n < 4; ++n) {
                int gj = wn * 64 + n * 16 + fr;
#pragma unroll
                for (int qq = 0; qq < 4; ++qq)
                    uLds[(li0 + qq) * 132 + gj] = f2bf(-(&dv.x)[qq] * acc[m][n][qq]);
            }
        }
    }
    // ---- phase 2: projection (first gemm's barrier publishes uLds) ----
    long row0 = (long)b * 512 + tm * 128;
    f32x4 acc2[4][4] = {};
    gemm_bt_core(t0 + row0 * D_, D_, wTl,          D_, D_, As, Bs, acc2, true);
    gemm_bt_core(t1 + row0 * D_, D_, wTl + 16384,  D_, D_, As, Bs, acc2, true);
    // u-term: B = m2 staged, A-frags straight from uLds
    for (int s2 = 0; s2 < 2; ++s2) {
        __syncthreads();
        stage_rowmajor(wTl + 32768, 128, s2 * 64, Bs, tid);
        __syncthreads();
#pragma unroll
        for (int ks = 0; ks < 2; ++ks) {
            short8 a[4], bfr[4];
#pragma unroll
            for (int m = 0; m < 4; ++m)
                a[m] = *(const short8*)(uLds + (wm * 64 + m * 16 + fr) * 132 + s2 * 64 + ks * 32 + ko);
#pragma unroll
            for (int n = 0; n < 4; ++n)
                bfr[n] = *(const short8*)(Bs + (wn * 64 + n * 16 + fr) * 64 + ks * 32 + ko);
#pragma unroll
            for (int m = 0; m < 4; ++m)
#pragma unroll
                for (int n = 0; n < 4; ++n)
                    acc2[m][n] = __builtin_amdgcn_mfma_f32_16x16x32_bf16(
                        a[m], bfr[n], acc2[m][n], 0, 0, 0);
        }
    }
    // ---- epilogue ----
#pragma unroll
    for (int m = 0; m < 4; ++m) {
        long gr0 = row0 + wm * 64 + m * 16 + ((lane >> 4) << 2);
        float4 dv;
        if (LAYER == 1) dv = *(const float4*)(dinv + gr0);
#pragma unroll
        for (int n = 0; n < 4; ++n) {
            int gj = wn * 64 + n * 16 + (lane & 15);
            bf16x4 tw;
#pragma unroll
            for (int qq = 0; qq < 4; ++qq) {
                long gr = gr0 + qq;
                float v = fmaxf(acc2[m][n][qq] + bias[gj], 0.0f);
                if (LAYER == 1) {
                    ybf[gr * D_ + gj] = f2bf(v);
                    tw[qq] = f2bf((&dv.x)[qq] * v);
                } else {
                    out[gr * 640 + gj] = v;
                }
            }
            if (LAYER == 1)
                *(bf16x4*)(pTout + (gr0 >> 9) * 65536 + (long)gj * 512 + (gr0 & 511)) = tw;
        }
    }
}

// ---------------- host ----------------

extern "C" void kernel_launch(void* const* d_in, const int* in_sizes, int n_in,
                              void* d_out, int out_size, void* d_ws, size_t ws_size,
                              hipStream_t stream) {
    const int* seq    = (const int*)d_in[0];
    const int* recd   = (const int*)d_in[1];
    const float* etab = (const float*)d_in[2];
    const float* rtab = (const float*)d_in[3];
    const float* w1   = (const float*)d_in[4];
    const float* b1   = (const float*)d_in[5];
    const float* w2   = (const float*)d_in[6];
    const float* b2   = (const float*)d_in[7];
    float* out = (float*)d_out;
    char* ws = (char*)d_ws;

    if (ws_size < 151470592u) return;

    unsigned short* Abf  = (unsigned short*)(ws);
    unsigned short* feat = (unsigned short*)(ws + 67108864);
    unsigned short* pTa  = (unsigned short*)(ws + 67108864);   // aliases feat (dead after adj)
    unsigned short* pTb  = (unsigned short*)(ws + 83886080);
    unsigned short* t1   = (unsigned short*)(ws + 100663296);
    unsigned short* xbf  = (unsigned short*)(ws + 134217728);  // x, becomes y
    unsigned short* wT   = (unsigned short*)(ws + 150994944);
    float* psum = (float*)(ws + 151191552);
    float* pcnt = (float*)(ws + 151199744);
    float* dinv = (float*)(ws + 151208448);

    k_front<<<20864, 256, 0, stream>>>(recd, rtab, seq, etab, w1, w2, out, feat, xbf, wT);
    k_adj<<<1280, 256, 0, stream>>>(feat, Abf, psum, pcnt);
    k_degtrs<<<1024, 256, 0, stream>>>(Abf, psum, pcnt, xbf, dinv, pTa);
    // layer 1
    k_sxm<<<512, 256, 0, stream>>>(Abf, dinv, pTa, t1, pTb);                    // t1 = Sx, pTb
    k_sxp<1><<<512, 256, 0, stream>>>(Abf, dinv, pTb, xbf, t1, wT, b1,
                                      xbf, pTa, nullptr);                       // y->xbf, pTa
    // layer 2
    k_sxm<<<512, 256, 0, stream>>>(Abf, dinv, pTa, t1, pTb);
    k_sxp<2><<<512, 256, 0, stream>>>(Abf, dinv, pTb, xbf, t1, wT + 49152, b2,
                                      nullptr, nullptr, out);
}

// Round 8
// 225.869 us; speedup vs baseline: 1.8195x; 1.0324x over previous
//
#include <hip/hip_runtime.h>
#include <hip/hip_bf16.h>

typedef __attribute__((ext_vector_type(8))) unsigned short ushort8;
typedef __attribute__((ext_vector_type(4))) unsigned short bf16x4;
typedef __attribute__((ext_vector_type(8))) short short8;
typedef __attribute__((ext_vector_type(4))) float f32x4;
typedef __attribute__((ext_vector_type(2))) unsigned long long u64x2;

#define DEV __device__ __forceinline__

DEV unsigned short f2bf(float f) {
    unsigned u = __builtin_bit_cast(unsigned, f);
    return (unsigned short)((u + 0x7fffu + ((u >> 16) & 1u)) >> 16);
}
DEV float bf2f(unsigned short h) {
    unsigned u = ((unsigned)h) << 16;
    return __builtin_bit_cast(float, u);
}
DEV float wred(float v) {
#pragma unroll
    for (int m = 32; m > 0; m >>= 1) v += __shfl_xor(v, m, 64);
    return v;
}

constexpr int N_ = 512, D_ = 128, R_ = 512;
constexpr long NN2 = (long)N_ * N_;          // 262144

// async global->LDS, 16B per lane. LDS dest = wave-uniform base + lane*16.
// GLOBAL source is per-lane -> gather-staging works.
DEV void gll16(const void* g, void* l) {
    __builtin_amdgcn_global_load_lds(
        (const __attribute__((address_space(1))) unsigned*)g,
        (__attribute__((address_space(3))) unsigned*)l, 16, 0, 0);
}

// ---------------- fused front: gather_app | gather_x | wT | rtab->bf16 ----------------

__global__ __launch_bounds__(256) void k_front(const int* __restrict__ recd,
                                               const float* __restrict__ rtab,
                                               const int* __restrict__ seq,
                                               const float* __restrict__ etab,
                                               const float* __restrict__ w1,
                                               const float* __restrict__ w2,
                                               float* __restrict__ out,
                                               unsigned short* __restrict__ x,
                                               unsigned short* __restrict__ wT,
                                               unsigned short* __restrict__ rtb,
                                               float* __restrict__ rnorm) {
    int bid = blockIdx.x, tid = threadIdx.x;
    if (bid < 16384) {                       // ---- gather_app: out cols 128..639 + rnorm ----
        int lane = tid & 63, w = tid >> 6;
        long r = (long)bid * 4 + w;
        int tok = recd[r];
        const float* src = rtab + (long)tok * R_;
        int j = lane * 8;
        float4 v0 = *(const float4*)(src + j);
        float4 v1 = *(const float4*)(src + j + 4);
        float ssq = v0.x*v0.x + v0.y*v0.y + v0.z*v0.z + v0.w*v0.w
                  + v1.x*v1.x + v1.y*v1.y + v1.z*v1.z + v1.w*v1.w;
        ssq = wred(ssq);
        float* o = out + r * 640 + 128 + j;
        *(float4*)o = v0;
        *(float4*)(o + 4) = v1;
        if (lane == 0) rnorm[r] = 1.0f / fmaxf(sqrtf(ssq), 1e-12f);
    } else if (bid < 20480) {                // ---- gather_x ----
        long e8 = ((long)(bid - 16384) * 256 + tid) * 8;
        long r = e8 >> 7;
        int d0 = (int)(e8 & 127);
        int tok = seq[r];
        const float* src = etab + (long)tok * D_ + d0;
        float4 v0 = *(const float4*)src, v1 = *(const float4*)(src + 4);
        ushort8 u;
        u[0]=f2bf(v0.x); u[1]=f2bf(v0.y); u[2]=f2bf(v0.z); u[3]=f2bf(v0.w);
        u[4]=f2bf(v1.x); u[5]=f2bf(v1.y); u[6]=f2bf(v1.z); u[7]=f2bf(v1.w);
        *(ushort8*)(x + e8) = u;
    } else if (bid < 20864) {                // ---- wT (folded weights) ----
        int o = (bid - 20480) * 256 + tid;   // < 98304
        int l = o / 49152;
        int rr = o - l * 49152;
        int mat = rr >> 14;
        int e2 = rr & 16383;
        int e = e2 >> 7, d = e2 & 127;
        const float* w = l ? w2 : w1;
        float v;
        if (mat == 0)      v = w[d * 128 + e] - w[32768 + d * 128 + e];
        else if (mat == 1) v = w[16384 + d * 128 + e];
        else               v = 2.0f * w[32768 + d * 128 + e];
        wT[o] = f2bf(v);
    } else {                                 // ---- rtab -> bf16 copy (5000x512) ----
        long e8 = ((long)(bid - 20864) * 256 + tid) * 8;   // < 2,560,000
        float4 v0 = *(const float4*)(rtab + e8), v1 = *(const float4*)(rtab + e8 + 4);
        ushort8 u;
        u[0]=f2bf(v0.x); u[1]=f2bf(v0.y); u[2]=f2bf(v0.z); u[3]=f2bf(v0.w);
        u[4]=f2bf(v1.x); u[5]=f2bf(v1.y); u[6]=f2bf(v1.z); u[7]=f2bf(v1.w);
        *(ushort8*)(rtb + e8) = u;
    }
}

// ---------------- staging helpers ----------------

DEV void stage_rowmajor(const unsigned short* base, long ld, int k0,
                        unsigned short* dst, int tid) {
#pragma unroll
    for (int i = 0; i < 4; ++i) {
        int u = i * 256 + tid;        // 0..1023 16B units (128 rows x 64)
        int r = u >> 3, c = (u & 7) * 8;
        gll16(base + (long)r * ld + k0 + c,
              dst + i * 2048 + (tid & 448) * 8);
    }
}

// 128 rows x 128 cols panel from row-major [*, 512] source
DEV void stage_panel128(const unsigned short* base, int k0,
                        unsigned short* dst, int tid) {
#pragma unroll
    for (int i = 0; i < 8; ++i) {
        int u = i * 256 + tid;        // 0..2047 16B units
        int r = u >> 4, c = (u & 15) * 8;
        gll16(base + (long)r * 512 + k0 + c,
              dst + i * 2048 + (tid & 448) * 8);
    }
}

// gather-stage 128 rows x 64 cols from token-indexed table rows
DEV void stage_gather(const unsigned short* tab, const int* toks, int k0,
                      unsigned short* dst, int tid) {
#pragma unroll
    for (int i = 0; i < 4; ++i) {
        int u = i * 256 + tid;
        int r = u >> 3, c = (u & 7) * 8;
        gll16(tab + (long)toks[r] * 512 + k0 + c,
              dst + i * 2048 + (tid & 448) * 8);
    }
}

// dual=false: B panel identical to A panel; stage once, read b-frags from As.
DEV void gemm_bt_core(const unsigned short* Abase, long ldA,
                      const unsigned short* Bbase, long ldB, int K,
                      unsigned short* As, unsigned short* Bs,
                      f32x4 acc[4][4], bool dual) {
    int tid = threadIdx.x, lane = tid & 63, wave = tid >> 6;
    int wm = wave >> 1, wn = wave & 1;
    int fr = lane & 15, ko = (lane >> 4) * 8;
    const unsigned short* Bsrc = dual ? Bs : As;
    for (int k0 = 0; k0 < K; k0 += 64) {
        __syncthreads();
        stage_rowmajor(Abase, ldA, k0, As, tid);
        if (dual) stage_rowmajor(Bbase, ldB, k0, Bs, tid);
        __syncthreads();
#pragma unroll
        for (int ks = 0; ks < 2; ++ks) {
            short8 a[4], b[4];
#pragma unroll
            for (int m = 0; m < 4; ++m)
                a[m] = *(const short8*)(As + (wm * 64 + m * 16 + fr) * 64 + ks * 32 + ko);
#pragma unroll
            for (int n = 0; n < 4; ++n)
                b[n] = *(const short8*)(Bsrc + (wn * 64 + n * 16 + fr) * 64 + ks * 32 + ko);
#pragma unroll
            for (int m = 0; m < 4; ++m)
#pragma unroll
                for (int n = 0; n < 4; ++n)
                    acc[m][n] = __builtin_amdgcn_mfma_f32_16x16x32_bf16(
                        a[m], b[n], acc[m][n], 0, 0, 0);
        }
    }
}

// ---------------- adjacency: gather-staged from rtab_bf16, epilogue-normalized ----
// A_ij = dot(raw_i, raw_j) * rn_i * rn_j  (== cosine of f32-normalized rows, up to bf16 rounding)

__global__ __launch_bounds__(256) void k_adj(const unsigned short* __restrict__ rtb,
                                             const int* __restrict__ recd,
                                             const float* __restrict__ rnorm,
                                             unsigned short* __restrict__ Abf,
                                             float* __restrict__ psum,
                                             float* __restrict__ pcnt) {
    __shared__ __align__(16) unsigned short As[128 * 64], Bs[128 * 64];
    __shared__ int toks[256];
    __shared__ float sred[4], cred[4];
    int g = blockIdx.x;
    int r8 = g & 7, q = g >> 3;
    int q10 = q / 10;
    int b = r8 + (q10 << 3);
    int t = q - q10 * 10;               // 0..9 upper-triangle tile id
    int tm = (t < 4) ? 0 : (t < 7) ? 1 : (t < 9) ? 2 : 3;
    int tn = t - (tm * (9 - tm)) / 2 + tm;
    bool diag = (tm == tn);
    int tid = threadIdx.x, lane = tid & 63, wave = tid >> 6;
    if (tid < 128) toks[tid] = recd[b * 512 + tm * 128 + tid];
    else           toks[tid] = recd[b * 512 + tn * 128 + (tid - 128)];
    int wm = wave >> 1, wn = wave & 1;
    int fr = lane & 15, ko = (lane >> 4) * 8;
    f32x4 acc[4][4] = {};
    for (int k0 = 0; k0 < 512; k0 += 64) {
        __syncthreads();                      // first iter also publishes toks
        stage_gather(rtb, toks, k0, As, tid);
        if (!diag) stage_gather(rtb, toks + 128, k0, Bs, tid);
        __syncthreads();
        const unsigned short* Bsrc = diag ? As : Bs;
#pragma unroll
        for (int ks = 0; ks < 2; ++ks) {
            short8 a[4], bb[4];
#pragma unroll
            for (int m = 0; m < 4; ++m)
                a[m] = *(const short8*)(As + (wm * 64 + m * 16 + fr) * 64 + ks * 32 + ko);
#pragma unroll
            for (int n = 0; n < 4; ++n)
                bb[n] = *(const short8*)(Bsrc + (wn * 64 + n * 16 + fr) * 64 + ks * 32 + ko);
#pragma unroll
            for (int m = 0; m < 4; ++m)
#pragma unroll
                for (int n = 0; n < 4; ++n)
                    acc[m][n] = __builtin_amdgcn_mfma_f32_16x16x32_bf16(
                        a[m], bb[n], acc[m][n], 0, 0, 0);
        }
    }
    float s = 0.f, c = 0.f;
    unsigned short* Ab = Abf + (long)b * NN2;
    const float* rnb = rnorm + (long)b * 512;
#pragma unroll
    for (int m = 0; m < 4; ++m) {
        int gi0 = tm * 128 + wm * 64 + m * 16 + (lane >> 4) * 4;
        float4 rni = *(const float4*)(rnb + gi0);
#pragma unroll
        for (int n = 0; n < 4; ++n) {
            int gj = tn * 128 + wn * 64 + n * 16 + fr;
            float rj = rnb[gj];
            f32x4 v = acc[m][n];
            bf16x4 tw;
#pragma unroll
            for (int qq = 0; qq < 4; ++qq) {
                int gi = gi0 + qq;
                float vv = v[qq] * (&rni.x)[qq] * rj;
                unsigned short bv = f2bf(vv);
                Ab[(long)gi * N_ + gj] = bv;
                tw[qq] = bv;
                if (gj > gi) {
                    s += vv;
                    c += (vv != 0.0f) ? 1.0f : 0.0f;
                }
            }
            if (!diag)   // mirror: A[gj][gi0..gi0+3]
                *(bf16x4*)(Ab + (long)gj * N_ + gi0) = tw;
        }
    }
    s = wred(s);
    c = wred(c);
    if (lane == 0) { sred[wave] = s; cred[wave] = c; }
    __syncthreads();
    if (tid == 0) {
        psum[b * 16 + t] = sred[0] + sred[1] + sred[2] + sred[3];
        pcnt[b * 16 + t] = cred[0] + cred[1] + cred[2] + cred[3];
    }
}

// ---------------- fused: mean + mask + dinv + scale-transpose ----------------
__global__ __launch_bounds__(256) void k_degtrs(unsigned short* __restrict__ Abf,
                                                const float* __restrict__ psum,
                                                const float* __restrict__ pcnt,
                                                const unsigned short* __restrict__ xin,
                                                float* __restrict__ dinv,
                                                unsigned short* __restrict__ pT) {
    __shared__ unsigned char mb[4][64];
    __shared__ float sdinv[64];
    __shared__ unsigned short t[64 * 128];
    int bid = blockIdx.x;
    int b = bid >> 3, tn = bid & 7;
    int tid = threadIdx.x, lane = tid & 63, w = tid >> 6;
    float s = 0.f, c = 0.f;
#pragma unroll
    for (int k = 0; k < 10; ++k) { s += psum[b * 16 + k]; c += pcnt[b * 16 + k]; }
    float m = s / fmaxf(c, 1.0f);
#pragma unroll 1
    for (int i = 0; i < 16; ++i) {
        int rl = w * 16 + i;
        long r = (long)b * 512 + tn * 64 + rl;
        int ig = tn * 64 + rl;               // diagonal column for this row
        ushort8 v = *(const ushort8*)(Abf + r * 512 + lane * 8);
        unsigned byt = 0;
        int cnt = 0;
#pragma unroll
        for (int k = 0; k < 8; ++k) {
            float f = bf2f(v[k]);
            int j = lane * 8 + k;
            bool keep = (f >= m) && (f != 0.0f) && (j != ig);
            byt |= (keep ? 1u : 0u) << k;
            cnt += keep ? 1 : 0;
        }
        mb[w][lane] = (unsigned char)byt;
        float fc = wred((float)cnt);
        if (lane < 8) {
            unsigned long long mword = *(const unsigned long long*)&mb[w][lane * 8];
            *(unsigned long long*)((unsigned char*)Abf + r * 1024 + lane * 8) = mword;
        }
        if (lane == 8) {
            float dv = (fc > 0.f) ? rsqrtf(fc) : 0.f;
            dinv[r] = dv;
            sdinv[rl] = dv;
        }
    }
    __syncthreads();
    // phase C: scale-transpose x tile [64n x 128d] -> pT[b][d][tn*64+n]
    const unsigned short* ib = xin + ((long)b * 512 + tn * 64) * 128;
    unsigned short* ob = pT + (long)b * 65536 + tn * 64;
#pragma unroll
    for (int i = 0; i < 4; ++i) {
        int u = i * 256 + tid;          // 1024 ushort8 units
        int n = u >> 4, g = u & 15;
        float sc = sdinv[n];
        ushort8 v = *(const ushort8*)(ib + n * 128 + g * 8);
        ushort8 sv;
#pragma unroll
        for (int tt = 0; tt < 8; ++tt) sv[tt] = f2bf(bf2f(v[tt]) * sc);
        int gs = g ^ ((n >> 3) & 7);
        *(ushort8*)(t + n * 128 + gs * 8) = sv;
    }
    __syncthreads();
#pragma unroll
    for (int i = 0; i < 4; ++i) {
        int u = i * 256 + tid;
        int d = u >> 3, n8 = (u & 7) * 8;
        ushort8 v;
#pragma unroll
        for (int tt = 0; tt < 8; ++tt) {
            int n = n8 + tt;
            int g = (d >> 3) ^ ((n >> 3) & 7);
            v[tt] = t[n * 128 + g * 8 + (d & 7)];
        }
        *(ushort8*)(ob + (long)d * 512 + n8) = v;
    }
}

// ---------------- masked S-GEMM (t1 pass), BK=128: writes t1 + (Dinv t1)^T ----------------
__global__ __launch_bounds__(256) void k_sxm(const unsigned short* __restrict__ Abf,
                                             const float* __restrict__ dinv,
                                             const unsigned short* __restrict__ pT,
                                             unsigned short* __restrict__ outN,
                                             unsigned short* __restrict__ outT) {
    __shared__ __align__(16) unsigned short Bs[128 * 128];
    __shared__ __align__(8) unsigned short lut4[16 * 4];
    int tid = threadIdx.x, lane = tid & 63, wave = tid >> 6;
    if (tid < 16) {   // nibble -> 4 bf16 {0,1}, conflict-free banks
        unsigned long long e = 0;
#pragma unroll
        for (int j = 0; j < 4; ++j)
            if ((tid >> j) & 1) e |= 0x3F80ull << (16 * j);
        *(unsigned long long*)(lut4 + tid * 4) = e;
    }
    int g = blockIdx.x;
    int r = g & 7, q = g >> 3;
    int b = r + ((q >> 2) << 3);
    int tm = q & 3;
    int wm = wave >> 1, wn = wave & 1;
    int fr = lane & 15, ko = (lane >> 4) * 8;
    const unsigned char* mbase = (const unsigned char*)Abf + (long)b * 524288;
    const unsigned short* pb = pT + (long)b * 65536;
    f32x4 acc[4][4] = {};
    for (int k0 = 0; k0 < 512; k0 += 128) {
        __syncthreads();
        stage_panel128(pb, k0, Bs, tid);
        u64x2 mw[4];
#pragma unroll
        for (int m = 0; m < 4; ++m) {
            int row = tm * 128 + wm * 64 + m * 16 + fr;
            mw[m] = *(const u64x2*)(mbase + (long)row * 1024 + (k0 >> 3));
        }
        __syncthreads();
#pragma unroll
        for (int ks = 0; ks < 4; ++ks) {
            short8 a4[4], b4[4];
#pragma unroll
            for (int m = 0; m < 4; ++m) {
                unsigned w32 = (unsigned)(mw[m][ks >> 1] >> ((ks & 1) * 32));
                unsigned byt = (w32 >> ko) & 255u;
                unsigned long long lo = *(const unsigned long long*)(lut4 + (byt & 15u) * 4);
                unsigned long long hi = *(const unsigned long long*)(lut4 + (byt >> 4) * 4);
                u64x2 tt; tt[0] = lo; tt[1] = hi;
                a4[m] = __builtin_bit_cast(short8, tt);
            }
#pragma unroll
            for (int n = 0; n < 4; ++n)
                b4[n] = *(const short8*)(Bs + (wn * 64 + n * 16 + fr) * 128 + ks * 32 + ko);
#pragma unroll
            for (int m = 0; m < 4; ++m)
#pragma unroll
                for (int n = 0; n < 4; ++n)
                    acc[m][n] = __builtin_amdgcn_mfma_f32_16x16x32_bf16(
                        a4[m], b4[n], acc[m][n], 0, 0, 0);
        }
    }
    unsigned short* on = outN + (long)b * 65536;
#pragma unroll
    for (int m = 0; m < 4; ++m) {
        int gi0 = tm * 128 + wm * 64 + m * 16 + ((lane >> 4) << 2);
        float4 dv = *(const float4*)(dinv + (long)b * 512 + gi0);
#pragma unroll
        for (int n = 0; n < 4; ++n) {
            int gj = wn * 64 + n * 16 + fr;
            bf16x4 tw;
#pragma unroll
            for (int qq = 0; qq < 4; ++qq) {
                float dq = (&dv.x)[qq];
                float t1v = -dq * acc[m][n][qq];
                on[(long)(gi0 + qq) * 128 + gj] = f2bf(t1v);
                tw[qq] = f2bf(dq * t1v);
            }
            *(bf16x4*)(outT + (long)b * 65536 + (long)gj * 512 + gi0) = tw;
        }
    }
}

// ---------------- fused: u = S t1 (masked, BK=128, in-LDS) + 3-term projection ----------------
template <int LAYER>
__global__ __launch_bounds__(256) void k_sxp(const unsigned short* __restrict__ Abf,
                                             const float* __restrict__ dinv,
                                             const unsigned short* __restrict__ pTin,
                                             const unsigned short* __restrict__ t0,
                                             const unsigned short* __restrict__ t1,
                                             const unsigned short* __restrict__ wTl,
                                             const float* __restrict__ bias,
                                             unsigned short* __restrict__ ybf,
                                             unsigned short* __restrict__ pTout,
                                             float* __restrict__ out) {
    __shared__ __align__(16) unsigned short AsBs[128 * 128];   // phase1: B-panel; phase2: As|Bs
    __shared__ __align__(16) unsigned short uLds[128 * 132];
    __shared__ __align__(8) unsigned short lut4[16 * 4];
    int tid = threadIdx.x, lane = tid & 63, wave = tid >> 6;
    if (tid < 16) {
        unsigned long long e = 0;
#pragma unroll
        for (int j = 0; j < 4; ++j)
            if ((tid >> j) & 1) e |= 0x3F80ull << (16 * j);
        *(unsigned long long*)(lut4 + tid * 4) = e;
    }
    int g = blockIdx.x;
    int r = g & 7, q = g >> 3;
    int b = r + ((q >> 2) << 3);
    int tm = q & 3;
    int wm = wave >> 1, wn = wave & 1;
    int fr = lane & 15, ko = (lane >> 4) * 8;
    // ---- phase 1: u-acc = A_bin @ pTin (rows tm*128..+128), BK=128 ----
    {
        const unsigned char* mbase = (const unsigned char*)Abf + (long)b * 524288;
        const unsigned short* pb = pTin + (long)b * 65536;
        f32x4 acc[4][4] = {};
        for (int k0 = 0; k0 < 512; k0 += 128) {
            __syncthreads();
            stage_panel128(pb, k0, AsBs, tid);
            u64x2 mw[4];
#pragma unroll
            for (int m = 0; m < 4; ++m) {
                int row = tm * 128 + wm * 64 + m * 16 + fr;
                mw[m] = *(const u64x2*)(mbase + (long)row * 1024 + (k0 >> 3));
            }
            __syncthreads();
#pragma unroll
            for (int ks = 0; ks < 4; ++ks) {
                short8 a4[4], b4[4];
#pragma unroll
                for (int m = 0; m < 4; ++m) {
                    unsigned w32 = (unsigned)(mw[m][ks >> 1] >> ((ks & 1) * 32));
                    unsigned byt = (w32 >> ko) & 255u;
                    unsigned long long lo = *(const unsigned long long*)(lut4 + (byt & 15u) * 4);
                    unsigned long long hi = *(const unsigned long long*)(lut4 + (byt >> 4) * 4);
                    u64x2 tt; tt[0] = lo; tt[1] = hi;
                    a4[m] = __builtin_bit_cast(short8, tt);
                }
#pragma unroll
                for (int n = 0; n < 4; ++n)
                    b4[n] = *(const short8*)(AsBs + (wn * 64 + n * 16 + fr) * 128 + ks * 32 + ko);
#pragma unroll
                for (int m = 0; m < 4; ++m)
#pragma unroll
                    for (int n = 0; n < 4; ++n)
                        acc[m][n] = __builtin_amdgcn_mfma_f32_16x16x32_bf16(
                            a4[m], b4[n], acc[m][n], 0, 0, 0);
            }
        }
        // park u = bf16(-dinv * acc) in LDS [row][col], LD=132 (pad kills conflicts)
#pragma unroll
        for (int m = 0; m < 4; ++m) {
            int li0 = wm * 64 + m * 16 + ((lane >> 4) << 2);   // local row
            float4 dv = *(const float4*)(dinv + (long)b * 512 + tm * 128 + li0);
#pragma unroll
            for (int n = 0; n < 4; ++n) {
                int gj = wn * 64 + n * 16 + fr;
#pragma unroll
                for (int qq = 0; qq < 4; ++qq)
                    uLds[(li0 + qq) * 132 + gj] = f2bf(-(&dv.x)[qq] * acc[m][n][qq]);
            }
        }
    }
    // ---- phase 2: projection ----
    unsigned short* As = AsBs;
    unsigned short* Bs = AsBs + 8192;
    long row0 = (long)b * 512 + tm * 128;
    f32x4 acc2[4][4] = {};
    gemm_bt_core(t0 + row0 * D_, D_, wTl,          D_, D_, As, Bs, acc2, true);
    gemm_bt_core(t1 + row0 * D_, D_, wTl + 16384,  D_, D_, As, Bs, acc2, true);
    // u-term: B = m2 staged, A-frags straight from uLds
    for (int s2 = 0; s2 < 2; ++s2) {
        __syncthreads();
        stage_rowmajor(wTl + 32768, 128, s2 * 64, Bs, tid);
        __syncthreads();
#pragma unroll
        for (int ks = 0; ks < 2; ++ks) {
            short8 a[4], bfr[4];
#pragma unroll
            for (int m = 0; m < 4; ++m)
                a[m] = *(const short8*)(uLds + (wm * 64 + m * 16 + fr) * 132 + s2 * 64 + ks * 32 + ko);
#pragma unroll
            for (int n = 0; n < 4; ++n)
                bfr[n] = *(const short8*)(Bs + (wn * 64 + n * 16 + fr) * 64 + ks * 32 + ko);
#pragma unroll
            for (int m = 0; m < 4; ++m)
#pragma unroll
                for (int n = 0; n < 4; ++n)
                    acc2[m][n] = __builtin_amdgcn_mfma_f32_16x16x32_bf16(
                        a[m], bfr[n], acc2[m][n], 0, 0, 0);
        }
    }
    // ---- epilogue ----
#pragma unroll
    for (int m = 0; m < 4; ++m) {
        long gr0 = row0 + wm * 64 + m * 16 + ((lane >> 4) << 2);
        float4 dv;
        if (LAYER == 1) dv = *(const float4*)(dinv + gr0);
#pragma unroll
        for (int n = 0; n < 4; ++n) {
            int gj = wn * 64 + n * 16 + (lane & 15);
            bf16x4 tw;
#pragma unroll
            for (int qq = 0; qq < 4; ++qq) {
                long gr = gr0 + qq;
                float v = fmaxf(acc2[m][n][qq] + bias[gj], 0.0f);
                if (LAYER == 1) {
                    ybf[gr * D_ + gj] = f2bf(v);
                    tw[qq] = f2bf((&dv.x)[qq] * v);
                } else {
                    out[gr * 640 + gj] = v;
                }
            }
            if (LAYER == 1)
                *(bf16x4*)(pTout + (gr0 >> 9) * 65536 + (long)gj * 512 + (gr0 & 511)) = tw;
        }
    }
}

// ---------------- host ----------------

extern "C" void kernel_launch(void* const* d_in, const int* in_sizes, int n_in,
                              void* d_out, int out_size, void* d_ws, size_t ws_size,
                              hipStream_t stream) {
    const int* seq    = (const int*)d_in[0];
    const int* recd   = (const int*)d_in[1];
    const float* etab = (const float*)d_in[2];
    const float* rtab = (const float*)d_in[3];
    const float* w1   = (const float*)d_in[4];
    const float* b1   = (const float*)d_in[5];
    const float* w2   = (const float*)d_in[6];
    const float* b2   = (const float*)d_in[7];
    float* out = (float*)d_out;
    char* ws = (char*)d_ws;

    // workspace layout (bytes):
    //   [0,64M)        A bf16 (+ per-row 64B bitmask at row starts after degtrs)
    //   [64M,..) 16MB slots: pTa @64M, pTb @80M, {rtab_bf @112M (5.1MB), rnorm @+5.25M}
    //   t1 @96M, xbf @128M (x then y), wT @144M, psum/pcnt/dinv after
    if (ws_size < 151470592u) return;

    unsigned short* Abf  = (unsigned short*)(ws);
    unsigned short* pTa  = (unsigned short*)(ws + 67108864);
    unsigned short* pTb  = (unsigned short*)(ws + 83886080);
    unsigned short* t1   = (unsigned short*)(ws + 100663296);
    unsigned short* rtb  = (unsigned short*)(ws + 117440512);   // 5,120,000 B
    float* rnorm         = (float*)(ws + 122683392);            // 262,144 B
    unsigned short* xbf  = (unsigned short*)(ws + 134217728);
    unsigned short* wT   = (unsigned short*)(ws + 150994944);
    float* psum = (float*)(ws + 151191552);
    float* pcnt = (float*)(ws + 151199744);
    float* dinv = (float*)(ws + 151208448);

    k_front<<<22114, 256, 0, stream>>>(recd, rtab, seq, etab, w1, w2,
                                       out, xbf, wT, rtb, rnorm);
    k_adj<<<1280, 256, 0, stream>>>(rtb, recd, rnorm, Abf, psum, pcnt);
    k_degtrs<<<1024, 256, 0, stream>>>(Abf, psum, pcnt, xbf, dinv, pTa);
    // layer 1
    k_sxm<<<512, 256, 0, stream>>>(Abf, dinv, pTa, t1, pTb);                    // t1 = Sx, pTb
    k_sxp<1><<<512, 256, 0, stream>>>(Abf, dinv, pTb, xbf, t1, wT, b1,
                                      xbf, pTa, nullptr);                       // y->xbf, pTa
    // layer 2
    k_sxm<<<512, 256, 0, stream>>>(Abf, dinv, pTa, t1, pTb);
    k_sxp<2><<<512, 256, 0, stream>>>(Abf, dinv, pTb, xbf, t1, wT + 49152, b2,
                                      nullptr, nullptr, out);
}

// Round 9
// 222.881 us; speedup vs baseline: 1.8439x; 1.0134x over previous
//
#include <hip/hip_runtime.h>
#include <hip/hip_bf16.h>

typedef __attribute__((ext_vector_type(8))) unsigned short ushort8;
typedef __attribute__((ext_vector_type(4))) unsigned short bf16x4;
typedef __attribute__((ext_vector_type(8))) short short8;
typedef __attribute__((ext_vector_type(4))) float f32x4;
typedef __attribute__((ext_vector_type(2))) unsigned long long u64x2;

#define DEV __device__ __forceinline__

DEV unsigned short f2bf(float f) {
    unsigned u = __builtin_bit_cast(unsigned, f);
    return (unsigned short)((u + 0x7fffu + ((u >> 16) & 1u)) >> 16);
}
DEV float bf2f(unsigned short h) {
    unsigned u = ((unsigned)h) << 16;
    return __builtin_bit_cast(float, u);
}
DEV float wred(float v) {
#pragma unroll
    for (int m = 32; m > 0; m >>= 1) v += __shfl_xor(v, m, 64);
    return v;
}

constexpr int N_ = 512, D_ = 128, R_ = 512;
constexpr long NN2 = (long)N_ * N_;          // 262144
constexpr int PSTR = 520;                    // padded panel row stride (ushorts)
constexpr int USTR = 136;                    // padded uLds row stride

// async global->LDS, 16B per lane. LDS dest = wave-uniform base + lane*16.
// GLOBAL source is per-lane -> gather-staging works.
DEV void gll16(const void* g, void* l) {
    __builtin_amdgcn_global_load_lds(
        (const __attribute__((address_space(1))) unsigned*)g,
        (__attribute__((address_space(3))) unsigned*)l, 16, 0, 0);
}

// ---------------- fused front: gather_app | gather_x | wT | rtab->bf16 ----------------

__global__ __launch_bounds__(256) void k_front(const int* __restrict__ recd,
                                               const float* __restrict__ rtab,
                                               const int* __restrict__ seq,
                                               const float* __restrict__ etab,
                                               const float* __restrict__ w1,
                                               const float* __restrict__ w2,
                                               float* __restrict__ out,
                                               unsigned short* __restrict__ x,
                                               unsigned short* __restrict__ wT,
                                               unsigned short* __restrict__ rtb,
                                               float* __restrict__ rnorm) {
    int bid = blockIdx.x, tid = threadIdx.x;
    if (bid < 16384) {                       // ---- gather_app: out cols 128..639 + rnorm ----
        int lane = tid & 63, w = tid >> 6;
        long r = (long)bid * 4 + w;
        int tok = recd[r];
        const float* src = rtab + (long)tok * R_;
        int j = lane * 8;
        float4 v0 = *(const float4*)(src + j);
        float4 v1 = *(const float4*)(src + j + 4);
        float ssq = v0.x*v0.x + v0.y*v0.y + v0.z*v0.z + v0.w*v0.w
                  + v1.x*v1.x + v1.y*v1.y + v1.z*v1.z + v1.w*v1.w;
        ssq = wred(ssq);
        float* o = out + r * 640 + 128 + j;
        *(float4*)o = v0;
        *(float4*)(o + 4) = v1;
        if (lane == 0) rnorm[r] = 1.0f / fmaxf(sqrtf(ssq), 1e-12f);
    } else if (bid < 20480) {                // ---- gather_x ----
        long e8 = ((long)(bid - 16384) * 256 + tid) * 8;
        long r = e8 >> 7;
        int d0 = (int)(e8 & 127);
        int tok = seq[r];
        const float* src = etab + (long)tok * D_ + d0;
        float4 v0 = *(const float4*)src, v1 = *(const float4*)(src + 4);
        ushort8 u;
        u[0]=f2bf(v0.x); u[1]=f2bf(v0.y); u[2]=f2bf(v0.z); u[3]=f2bf(v0.w);
        u[4]=f2bf(v1.x); u[5]=f2bf(v1.y); u[6]=f2bf(v1.z); u[7]=f2bf(v1.w);
        *(ushort8*)(x + e8) = u;
    } else if (bid < 20864) {                // ---- wT (folded weights) ----
        int o = (bid - 20480) * 256 + tid;   // < 98304
        int l = o / 49152;
        int rr = o - l * 49152;
        int mat = rr >> 14;
        int e2 = rr & 16383;
        int e = e2 >> 7, d = e2 & 127;
        const float* w = l ? w2 : w1;
        float v;
        if (mat == 0)      v = w[d * 128 + e] - w[32768 + d * 128 + e];
        else if (mat == 1) v = w[16384 + d * 128 + e];
        else               v = 2.0f * w[32768 + d * 128 + e];
        wT[o] = f2bf(v);
    } else {                                 // ---- rtab -> bf16 copy (5000x512) ----
        long e8 = ((long)(bid - 20864) * 256 + tid) * 8;   // < 2,560,000
        float4 v0 = *(const float4*)(rtab + e8), v1 = *(const float4*)(rtab + e8 + 4);
        ushort8 u;
        u[0]=f2bf(v0.x); u[1]=f2bf(v0.y); u[2]=f2bf(v0.z); u[3]=f2bf(v0.w);
        u[4]=f2bf(v1.x); u[5]=f2bf(v1.y); u[6]=f2bf(v1.z); u[7]=f2bf(v1.w);
        *(ushort8*)(rtb + e8) = u;
    }
}

// ---------------- staging helpers (256-thread blocks) ----------------

DEV void stage_rowmajor(const unsigned short* base, long ld, int k0,
                        unsigned short* dst, int tid) {
#pragma unroll
    for (int i = 0; i < 4; ++i) {
        int u = i * 256 + tid;        // 0..1023 16B units (128 rows x 64)
        int r = u >> 3, c = (u & 7) * 8;
        gll16(base + (long)r * ld + k0 + c,
              dst + i * 2048 + (tid & 448) * 8);
    }
}

// gather-stage 128 rows x 64 cols from token-indexed table rows
DEV void stage_gather(const unsigned short* tab, const int* toks, int k0,
                      unsigned short* dst, int tid) {
#pragma unroll
    for (int i = 0; i < 4; ++i) {
        int u = i * 256 + tid;
        int r = u >> 3, c = (u & 7) * 8;
        gll16(tab + (long)toks[r] * 512 + k0 + c,
              dst + i * 2048 + (tid & 448) * 8);
    }
}

// ---------------- staging helpers (512-thread blocks) ----------------

// 256 rows x 64 cols, ld=128, dst rowstride 64
DEV void stageA256(const unsigned short* base, int k0, unsigned short* dst, int tid) {
    int w = tid >> 6;
#pragma unroll
    for (int i = 0; i < 4; ++i) {
        int u = i * 512 + tid;
        int r = u >> 3, c = (u & 7) * 8;
        gll16(base + (long)r * 128 + k0 + c, dst + (i * 64 + w * 8) * 64);
    }
}

// 128 rows x 64 cols, ld=128, dst rowstride 64
DEV void stageB128(const unsigned short* base, int k0, unsigned short* dst, int tid) {
    int w = tid >> 6;
#pragma unroll
    for (int i = 0; i < 2; ++i) {
        int u = i * 512 + tid;
        int r = u >> 3, c = (u & 7) * 8;
        gll16(base + (long)r * 128 + k0 + c, dst + (i * 64 + w * 8) * 64);
    }
}

// ---------------- adjacency (unchanged from R8) ----------------

__global__ __launch_bounds__(256) void k_adj(const unsigned short* __restrict__ rtb,
                                             const int* __restrict__ recd,
                                             const float* __restrict__ rnorm,
                                             unsigned short* __restrict__ Abf,
                                             float* __restrict__ psum,
                                             float* __restrict__ pcnt) {
    __shared__ __align__(16) unsigned short As[128 * 64], Bs[128 * 64];
    __shared__ int toks[256];
    __shared__ float sred[4], cred[4];
    int g = blockIdx.x;
    int r8 = g & 7, q = g >> 3;
    int q10 = q / 10;
    int b = r8 + (q10 << 3);
    int t = q - q10 * 10;               // 0..9 upper-triangle tile id
    int tm = (t < 4) ? 0 : (t < 7) ? 1 : (t < 9) ? 2 : 3;
    int tn = t - (tm * (9 - tm)) / 2 + tm;
    bool diag = (tm == tn);
    int tid = threadIdx.x, lane = tid & 63, wave = tid >> 6;
    if (tid < 128) toks[tid] = recd[b * 512 + tm * 128 + tid];
    else           toks[tid] = recd[b * 512 + tn * 128 + (tid - 128)];
    int wm = wave >> 1, wn = wave & 1;
    int fr = lane & 15, ko = (lane >> 4) * 8;
    f32x4 acc[4][4] = {};
    for (int k0 = 0; k0 < 512; k0 += 64) {
        __syncthreads();                      // first iter also publishes toks
        stage_gather(rtb, toks, k0, As, tid);
        if (!diag) stage_gather(rtb, toks + 128, k0, Bs, tid);
        __syncthreads();
        const unsigned short* Bsrc = diag ? As : Bs;
#pragma unroll
        for (int ks = 0; ks < 2; ++ks) {
            short8 a[4], bb[4];
#pragma unroll
            for (int m = 0; m < 4; ++m)
                a[m] = *(const short8*)(As + (wm * 64 + m * 16 + fr) * 64 + ks * 32 + ko);
#pragma unroll
            for (int n = 0; n < 4; ++n)
                bb[n] = *(const short8*)(Bsrc + (wn * 64 + n * 16 + fr) * 64 + ks * 32 + ko);
#pragma unroll
            for (int m = 0; m < 4; ++m)
#pragma unroll
                for (int n = 0; n < 4; ++n)
                    acc[m][n] = __builtin_amdgcn_mfma_f32_16x16x32_bf16(
                        a[m], bb[n], acc[m][n], 0, 0, 0);
        }
    }
    float s = 0.f, c = 0.f;
    unsigned short* Ab = Abf + (long)b * NN2;
    const float* rnb = rnorm + (long)b * 512;
#pragma unroll
    for (int m = 0; m < 4; ++m) {
        int gi0 = tm * 128 + wm * 64 + m * 16 + (lane >> 4) * 4;
        float4 rni = *(const float4*)(rnb + gi0);
#pragma unroll
        for (int n = 0; n < 4; ++n) {
            int gj = tn * 128 + wn * 64 + n * 16 + fr;
            float rj = rnb[gj];
            f32x4 v = acc[m][n];
            bf16x4 tw;
#pragma unroll
            for (int qq = 0; qq < 4; ++qq) {
                int gi = gi0 + qq;
                float vv = v[qq] * (&rni.x)[qq] * rj;
                unsigned short bv = f2bf(vv);
                Ab[(long)gi * N_ + gj] = bv;
                tw[qq] = bv;
                if (gj > gi) {
                    s += vv;
                    c += (vv != 0.0f) ? 1.0f : 0.0f;
                }
            }
            if (!diag)   // mirror: A[gj][gi0..gi0+3]
                *(bf16x4*)(Ab + (long)gj * N_ + gi0) = tw;
        }
    }
    s = wred(s);
    c = wred(c);
    if (lane == 0) { sred[wave] = s; cred[wave] = c; }
    __syncthreads();
    if (tid == 0) {
        psum[b * 16 + t] = sred[0] + sred[1] + sred[2] + sred[3];
        pcnt[b * 16 + t] = cred[0] + cred[1] + cred[2] + cred[3];
    }
}

// ---------------- fused: mean + mask + dinv + scale-transpose (XCD batch-affine) ----------------
__global__ __launch_bounds__(256) void k_degtrs(unsigned short* __restrict__ Abf,
                                                const float* __restrict__ psum,
                                                const float* __restrict__ pcnt,
                                                const unsigned short* __restrict__ xin,
                                                float* __restrict__ dinv,
                                                unsigned short* __restrict__ pT) {
    __shared__ unsigned char mb[4][64];
    __shared__ float sdinv[64];
    __shared__ unsigned short t[64 * 128];
    int bid = blockIdx.x;
    int q = bid >> 3, r8 = bid & 7;
    int b = r8 + ((q >> 3) << 3);       // same XCD as the k_adj blocks that wrote A[b]
    int tn = q & 7;
    int tid = threadIdx.x, lane = tid & 63, w = tid >> 6;
    float s = 0.f, c = 0.f;
#pragma unroll
    for (int k = 0; k < 10; ++k) { s += psum[b * 16 + k]; c += pcnt[b * 16 + k]; }
    float m = s / fmaxf(c, 1.0f);
#pragma unroll 1
    for (int i = 0; i < 16; ++i) {
        int rl = w * 16 + i;
        long r = (long)b * 512 + tn * 64 + rl;
        int ig = tn * 64 + rl;               // diagonal column for this row
        ushort8 v = *(const ushort8*)(Abf + r * 512 + lane * 8);
        unsigned byt = 0;
        int cnt = 0;
#pragma unroll
        for (int k = 0; k < 8; ++k) {
            float f = bf2f(v[k]);
            int j = lane * 8 + k;
            bool keep = (f >= m) && (f != 0.0f) && (j != ig);
            byt |= (keep ? 1u : 0u) << k;
            cnt += keep ? 1 : 0;
        }
        mb[w][lane] = (unsigned char)byt;
        float fc = wred((float)cnt);
        if (lane < 8) {
            unsigned long long mword = *(const unsigned long long*)&mb[w][lane * 8];
            *(unsigned long long*)((unsigned char*)Abf + r * 1024 + lane * 8) = mword;
        }
        if (lane == 8) {
            float dv = (fc > 0.f) ? rsqrtf(fc) : 0.f;
            dinv[r] = dv;
            sdinv[rl] = dv;
        }
    }
    __syncthreads();
    // phase C: scale-transpose x tile [64n x 128d] -> pT[b][d][tn*64+n]
    const unsigned short* ib = xin + ((long)b * 512 + tn * 64) * 128;
    unsigned short* ob = pT + (long)b * 65536 + tn * 64;
#pragma unroll
    for (int i = 0; i < 4; ++i) {
        int u = i * 256 + tid;          // 1024 ushort8 units
        int n = u >> 4, g = u & 15;
        float sc = sdinv[n];
        ushort8 v = *(const ushort8*)(ib + n * 128 + g * 8);
        ushort8 sv;
#pragma unroll
        for (int tt = 0; tt < 8; ++tt) sv[tt] = f2bf(bf2f(v[tt]) * sc);
        int gs = g ^ ((n >> 3) & 7);
        *(ushort8*)(t + n * 128 + gs * 8) = sv;
    }
    __syncthreads();
#pragma unroll
    for (int i = 0; i < 4; ++i) {
        int u = i * 256 + tid;
        int d = u >> 3, n8 = (u & 7) * 8;
        ushort8 v;
#pragma unroll
        for (int tt = 0; tt < 8; ++tt) {
            int n = n8 + tt;
            int g = (d >> 3) ^ ((n >> 3) & 7);
            v[tt] = t[n * 128 + g * 8 + (d & 7)];
        }
        *(ushort8*)(ob + (long)d * 512 + n8) = v;
    }
}

// ---------------- masked S-GEMM, full-panel-in-LDS, barrier-free K-loop ----------------
// 512 threads = 8 waves (4M x 2N); block = (batch b, half) -> 256 output rows.
// Panel pT[b] (128 d-rows x 512 k) staged once, row stride 520 (conflict-free b128).
__global__ __launch_bounds__(512) void k_sxm(const unsigned short* __restrict__ Abf,
                                             const float* __restrict__ dinv,
                                             const unsigned short* __restrict__ pT,
                                             unsigned short* __restrict__ outN,
                                             unsigned short* __restrict__ outT) {
    __shared__ __align__(16) unsigned short Ps[128 * PSTR];
    __shared__ __align__(8) unsigned short lut4[16 * 4];
    int tid = threadIdx.x, lane = tid & 63, w = tid >> 6;
    if (tid < 16) {   // nibble -> 4 bf16 {0,1}
        unsigned long long e = 0;
#pragma unroll
        for (int j = 0; j < 4; ++j)
            if ((tid >> j) & 1) e |= 0x3F80ull << (16 * j);
        *(unsigned long long*)(lut4 + tid * 4) = e;
    }
    int g = blockIdx.x;
    int xcd = g & 7, idx = g >> 3;          // idx 0..31
    int b = xcd + ((idx >> 1) << 3);        // XCD-affine batch
    int half = idx & 1;
    int wm = w >> 1, wn = w & 1;
    int fr = lane & 15, ko = (lane >> 4) * 8;
    const unsigned char* mbase = (const unsigned char*)Abf + (long)b * 524288;
    const unsigned short* pb = pT + (long)b * 65536;
    // stage full panel once: one row (1KB) per wave-instruction, padded stride
#pragma unroll
    for (int i = 0; i < 16; ++i) {
        int r = i * 8 + w;
        gll16(pb + (long)r * 512 + lane * 8, Ps + r * PSTR);
    }
    __syncthreads();
    f32x4 acc[4][4] = {};
    int rowbase = half * 256 + wm * 64;
#pragma unroll 1
    for (int k0 = 0; k0 < 512; k0 += 128) {
        u64x2 mw[4];
#pragma unroll
        for (int m = 0; m < 4; ++m) {
            int row = rowbase + m * 16 + fr;
            mw[m] = *(const u64x2*)(mbase + (long)row * 1024 + (k0 >> 3));
        }
#pragma unroll
        for (int kss = 0; kss < 4; ++kss) {
            short8 a4[4], b4[4];
#pragma unroll
            for (int m = 0; m < 4; ++m) {
                unsigned w32 = (unsigned)(mw[m][kss >> 1] >> ((kss & 1) * 32));
                unsigned byt = (w32 >> ko) & 255u;
                unsigned long long lo = *(const unsigned long long*)(lut4 + (byt & 15u) * 4);
                unsigned long long hi = *(const unsigned long long*)(lut4 + (byt >> 4) * 4);
                u64x2 tt; tt[0] = lo; tt[1] = hi;
                a4[m] = __builtin_bit_cast(short8, tt);
            }
#pragma unroll
            for (int n = 0; n < 4; ++n)
                b4[n] = *(const short8*)(Ps + (wn * 64 + n * 16 + fr) * PSTR + k0 + kss * 32 + ko);
#pragma unroll
            for (int m = 0; m < 4; ++m)
#pragma unroll
                for (int n = 0; n < 4; ++n)
                    acc[m][n] = __builtin_amdgcn_mfma_f32_16x16x32_bf16(
                        a4[m], b4[n], acc[m][n], 0, 0, 0);
        }
    }
    unsigned short* on = outN + (long)b * 65536;
#pragma unroll
    for (int m = 0; m < 4; ++m) {
        int gi0 = half * 256 + wm * 64 + m * 16 + ((lane >> 4) << 2);
        float4 dv = *(const float4*)(dinv + (long)b * 512 + gi0);
#pragma unroll
        for (int n = 0; n < 4; ++n) {
            int gj = wn * 64 + n * 16 + fr;
            bf16x4 tw;
#pragma unroll
            for (int qq = 0; qq < 4; ++qq) {
                float dq = (&dv.x)[qq];
                float t1v = -dq * acc[m][n][qq];
                on[(long)(gi0 + qq) * 128 + gj] = f2bf(t1v);
                tw[qq] = f2bf(dq * t1v);
            }
            *(bf16x4*)(outT + (long)b * 65536 + (long)gj * 512 + gi0) = tw;
        }
    }
}

// ---------------- fused: u = S t1 (full-panel phase) + 3-term projection ----------------
// 512 threads, block = (b, half) -> 256 rows. LDS: phase1 panel 128x520;
// phase2 reuses it as As[256x64] | Bs[128x64] | uLds[256][136].
template <int LAYER>
__global__ __launch_bounds__(512) void k_sxp(const unsigned short* __restrict__ Abf,
                                             const float* __restrict__ dinv,
                                             const unsigned short* __restrict__ pTin,
                                             const unsigned short* __restrict__ t0,
                                             const unsigned short* __restrict__ t1,
                                             const unsigned short* __restrict__ wTl,
                                             const float* __restrict__ bias,
                                             unsigned short* __restrict__ ybf,
                                             unsigned short* __restrict__ pTout,
                                             float* __restrict__ out) {
    __shared__ __align__(16) unsigned short lds[128 * PSTR];   // 133,120 B
    __shared__ __align__(8) unsigned short lut4[16 * 4];
    int tid = threadIdx.x, lane = tid & 63, w = tid >> 6;
    if (tid < 16) {
        unsigned long long e = 0;
#pragma unroll
        for (int j = 0; j < 4; ++j)
            if ((tid >> j) & 1) e |= 0x3F80ull << (16 * j);
        *(unsigned long long*)(lut4 + tid * 4) = e;
    }
    int g = blockIdx.x;
    int xcd = g & 7, idx = g >> 3;
    int b = xcd + ((idx >> 1) << 3);
    int half = idx & 1;
    int wm = w >> 1, wn = w & 1;
    int fr = lane & 15, ko = (lane >> 4) * 8;
    unsigned short* As  = lds;            // 256x64 (16384 ushorts)
    unsigned short* Bs  = lds + 16384;    // 128x64 (8192)
    unsigned short* uL  = lds + 24576;    // 256x136 (34816)
    // ---- phase 1: u rows [half*256,+256) = A_bin @ pTin, panel in LDS ----
    {
        const unsigned char* mbase = (const unsigned char*)Abf + (long)b * 524288;
        const unsigned short* pb = pTin + (long)b * 65536;
#pragma unroll
        for (int i = 0; i < 16; ++i) {
            int r = i * 8 + w;
            gll16(pb + (long)r * 512 + lane * 8, lds + r * PSTR);
        }
        __syncthreads();
        f32x4 acc[4][4] = {};
        int rowbase = half * 256 + wm * 64;
#pragma unroll 1
        for (int k0 = 0; k0 < 512; k0 += 128) {
            u64x2 mw[4];
#pragma unroll
            for (int m = 0; m < 4; ++m) {
                int row = rowbase + m * 16 + fr;
                mw[m] = *(const u64x2*)(mbase + (long)row * 1024 + (k0 >> 3));
            }
#pragma unroll
            for (int kss = 0; kss < 4; ++kss) {
                short8 a4[4], b4[4];
#pragma unroll
                for (int m = 0; m < 4; ++m) {
                    unsigned w32 = (unsigned)(mw[m][kss >> 1] >> ((kss & 1) * 32));
                    unsigned byt = (w32 >> ko) & 255u;
                    unsigned long long lo = *(const unsigned long long*)(lut4 + (byt & 15u) * 4);
                    unsigned long long hi = *(const unsigned long long*)(lut4 + (byt >> 4) * 4);
                    u64x2 tt; tt[0] = lo; tt[1] = hi;
                    a4[m] = __builtin_bit_cast(short8, tt);
                }
#pragma unroll
                for (int n = 0; n < 4; ++n)
                    b4[n] = *(const short8*)(lds + (wn * 64 + n * 16 + fr) * PSTR + k0 + kss * 32 + ko);
#pragma unroll
                for (int m = 0; m < 4; ++m)
#pragma unroll
                    for (int n = 0; n < 4; ++n)
                        acc[m][n] = __builtin_amdgcn_mfma_f32_16x16x32_bf16(
                            a4[m], b4[n], acc[m][n], 0, 0, 0);
            }
        }
        __syncthreads();    // all panel reads done before uL overwrites it
        // park u = bf16(-dinv*acc) in uLds [256][136]
#pragma unroll
        for (int m = 0; m < 4; ++m) {
            int li0 = wm * 64 + m * 16 + ((lane >> 4) << 2);   // 0..255
            float4 dv = *(const float4*)(dinv + (long)b * 512 + half * 256 + li0);
#pragma unroll
            for (int n = 0; n < 4; ++n) {
                int gj = wn * 64 + n * 16 + fr;
#pragma unroll
                for (int qq = 0; qq < 4; ++qq)
                    uL[(li0 + qq) * USTR + gj] = f2bf(-(&dv.x)[qq] * acc[m][n][qq]);
            }
        }
    }
    // ---- phase 2: y = relu(t0 m0 + t1 m1 + u m2 + bias) over 256 rows ----
    long row0 = (long)b * 512 + half * 256;
    f32x4 acc2[4][4] = {};
#pragma unroll 1
    for (int mat = 0; mat < 2; ++mat) {
        const unsigned short* tsrc = (mat == 0) ? (t0 + row0 * D_) : (t1 + row0 * D_);
        const unsigned short* wsrc = wTl + mat * 16384;
#pragma unroll 1
        for (int k0 = 0; k0 < 128; k0 += 64) {
            __syncthreads();
            stageA256(tsrc, k0, As, tid);
            stageB128(wsrc, k0, Bs, tid);
            __syncthreads();
#pragma unroll
            for (int ks = 0; ks < 2; ++ks) {
                short8 a[4], bfr[4];
#pragma unroll
                for (int m = 0; m < 4; ++m)
                    a[m] = *(const short8*)(As + (wm * 64 + m * 16 + fr) * 64 + ks * 32 + ko);
#pragma unroll
                for (int n = 0; n < 4; ++n)
                    bfr[n] = *(const short8*)(Bs + (wn * 64 + n * 16 + fr) * 64 + ks * 32 + ko);
#pragma unroll
                for (int m = 0; m < 4; ++m)
#pragma unroll
                    for (int n = 0; n < 4; ++n)
                        acc2[m][n] = __builtin_amdgcn_mfma_f32_16x16x32_bf16(
                            a[m], bfr[n], acc2[m][n], 0, 0, 0);
            }
        }
    }
    // u-term: A-frags from uLds
#pragma unroll 1
    for (int s2 = 0; s2 < 2; ++s2) {
        __syncthreads();
        stageB128(wTl + 32768, s2 * 64, Bs, tid);
        __syncthreads();
#pragma unroll
        for (int ks = 0; ks < 2; ++ks) {
            short8 a[4], bfr[4];
#pragma unroll
            for (int m = 0; m < 4; ++m)
                a[m] = *(const short8*)(uL + (wm * 64 + m * 16 + fr) * USTR + s2 * 64 + ks * 32 + ko);
#pragma unroll
            for (int n = 0; n < 4; ++n)
                bfr[n] = *(const short8*)(Bs + (wn * 64 + n * 16 + fr) * 64 + ks * 32 + ko);
#pragma unroll
            for (int m = 0; m < 4; ++m)
#pragma unroll
                for (int n = 0; n < 4; ++n)
                    acc2[m][n] = __builtin_amdgcn_mfma_f32_16x16x32_bf16(
                        a[m], bfr[n], acc2[m][n], 0, 0, 0);
        }
    }
    // ---- epilogue ----
#pragma unroll
    for (int m = 0; m < 4; ++m) {
        long gr0 = row0 + wm * 64 + m * 16 + ((lane >> 4) << 2);
        float4 dv;
        if (LAYER == 1) dv = *(const float4*)(dinv + gr0);
#pragma unroll
        for (int n = 0; n < 4; ++n) {
            int gj = wn * 64 + n * 16 + (lane & 15);
            bf16x4 tw;
#pragma unroll
            for (int qq = 0; qq < 4; ++qq) {
                long gr = gr0 + qq;
                float v = fmaxf(acc2[m][n][qq] + bias[gj], 0.0f);
                if (LAYER == 1) {
                    ybf[gr * D_ + gj] = f2bf(v);
                    tw[qq] = f2bf((&dv.x)[qq] * v);
                } else {
                    out[gr * 640 + gj] = v;
                }
            }
            if (LAYER == 1)
                *(bf16x4*)(pTout + (gr0 >> 9) * 65536 + (long)gj * 512 + (gr0 & 511)) = tw;
        }
    }
}

// ---------------- host ----------------

extern "C" void kernel_launch(void* const* d_in, const int* in_sizes, int n_in,
                              void* d_out, int out_size, void* d_ws, size_t ws_size,
                              hipStream_t stream) {
    const int* seq    = (const int*)d_in[0];
    const int* recd   = (const int*)d_in[1];
    const float* etab = (const float*)d_in[2];
    const float* rtab = (const float*)d_in[3];
    const float* w1   = (const float*)d_in[4];
    const float* b1   = (const float*)d_in[5];
    const float* w2   = (const float*)d_in[6];
    const float* b2   = (const float*)d_in[7];
    float* out = (float*)d_out;
    char* ws = (char*)d_ws;

    if (ws_size < 151470592u) return;

    unsigned short* Abf  = (unsigned short*)(ws);
    unsigned short* pTa  = (unsigned short*)(ws + 67108864);
    unsigned short* pTb  = (unsigned short*)(ws + 83886080);
    unsigned short* t1   = (unsigned short*)(ws + 100663296);
    unsigned short* rtb  = (unsigned short*)(ws + 117440512);   // 5,120,000 B
    float* rnorm         = (float*)(ws + 122683392);            // 262,144 B
    unsigned short* xbf  = (unsigned short*)(ws + 134217728);
    unsigned short* wT   = (unsigned short*)(ws + 150994944);
    float* psum = (float*)(ws + 151191552);
    float* pcnt = (float*)(ws + 151199744);
    float* dinv = (float*)(ws + 151208448);

    k_front<<<22114, 256, 0, stream>>>(recd, rtab, seq, etab, w1, w2,
                                       out, xbf, wT, rtb, rnorm);
    k_adj<<<1280, 256, 0, stream>>>(rtb, recd, rnorm, Abf, psum, pcnt);
    k_degtrs<<<1024, 256, 0, stream>>>(Abf, psum, pcnt, xbf, dinv, pTa);
    // layer 1
    k_sxm<<<256, 512, 0, stream>>>(Abf, dinv, pTa, t1, pTb);                    // t1 = Sx, pTb
    k_sxp<1><<<256, 512, 0, stream>>>(Abf, dinv, pTb, xbf, t1, wT, b1,
                                      xbf, pTa, nullptr);                       // y->xbf, pTa
    // layer 2
    k_sxm<<<256, 512, 0, stream>>>(Abf, dinv, pTa, t1, pTb);
    k_sxp<2><<<256, 512, 0, stream>>>(Abf, dinv, pTb, xbf, t1, wT + 49152, b2,
                                      nullptr, nullptr, out);
}